// Round 2
// baseline (622.408 us; speedup 1.0000x reference)
//
#include <hip/hip_runtime.h>
#include <hip/hip_bf16.h>

// Problem constants (B=4, M=4, L=1024, DM=768)
#define LM   4096   // interleaved sequence length L*M
#define D2   384    // d_inner/2
#define NCHK 64     // scan chunks
#define TCHK 64     // timesteps per chunk

__device__ __forceinline__ float siluf_(float x) { return x / (1.f + expf(-x)); }
__device__ __forceinline__ float softplusf_(float x) {
  return fmaxf(x, 0.f) + log1pf(expf(-fabsf(x)));
}

// ---------------------------------------------------------------------------
// K1: fused in-projection.  t = hidden @ w1^T -> LayerNorm -> exact GELU ->
//     xz = t @ w2^T, written modality-interleaved as x (d<384) / z (d>=384).
// grid (L/8, M, B), block 256.
// ---------------------------------------------------------------------------
__global__ __launch_bounds__(256) void k1_inproj(
    const float* __restrict__ hs, const float* __restrict__ w1g,
    const float* __restrict__ lng, const float* __restrict__ lnb,
    const float* __restrict__ w2g, const int* __restrict__ midx,
    float* __restrict__ xr, float* __restrict__ zr)
{
  __shared__ float hsl[8][772];     // 8 positions x 768 (+pad)
  __shared__ float w1s[16][772];
  __shared__ float w2s[768][20];    // 768 x 16 (+pad, keeps f4 alignment)
  __shared__ float tb[8][16];
  __shared__ float tb2[8][16];
  const int tid = threadIdx.x;
  const int l0 = blockIdx.x * 8;
  const int m  = blockIdx.y;
  const int b  = blockIdx.z;
  const int mi = midx[m];

  {
    const float4* p = (const float4*)(w1g + (size_t)mi * 16 * 768);
    for (int i = tid; i < 16 * 192; i += 256) {
      int r = i / 192, c = (i % 192) * 4;
      *(float4*)&w1s[r][c] = p[i];
    }
    const float4* q = (const float4*)(w2g + (size_t)mi * 768 * 16);
    for (int i = tid; i < 768 * 4; i += 256) {
      int dd = i / 4, c = (i % 4) * 4;
      *(float4*)&w2s[dd][c] = q[i];
    }
    const float4* hp = (const float4*)(hs + (((size_t)(b * 4 + m)) * 1024 + l0) * 768);
    for (int i = tid; i < 8 * 192; i += 256) {
      int r = i / 192, c = (i % 192) * 4;
      *(float4*)&hsl[r][c] = hp[i];
    }
  }
  __syncthreads();

  // phase 1: t[p][r] = dot768(hidden[p], w1[r]); microtile 4p x 4r, 32-way K-split
  {
    const int mt = tid >> 5;        // 0..7
    const int ks = tid & 31;
    const int p0 = (mt >> 2) * 4;   // 0,4
    const int r0 = (mt & 3) * 4;    // 0,4,8,12
    float acc[4][4] = {};
    #pragma unroll
    for (int jj = 0; jj < 6; jj++) {
      const int off = ks * 4 + jj * 128;   // spreads ks across banks
      float4 a[4], w[4];
      #pragma unroll
      for (int i = 0; i < 4; i++) a[i] = *(const float4*)&hsl[p0 + i][off];
      #pragma unroll
      for (int r = 0; r < 4; r++) w[r] = *(const float4*)&w1s[r0 + r][off];
      #pragma unroll
      for (int i = 0; i < 4; i++)
        #pragma unroll
        for (int r = 0; r < 4; r++)
          acc[i][r] += a[i].x * w[r].x + a[i].y * w[r].y + a[i].z * w[r].z + a[i].w * w[r].w;
    }
    #pragma unroll
    for (int i = 0; i < 4; i++)
      #pragma unroll
      for (int r = 0; r < 4; r++) {
        float v = acc[i][r];
        v += __shfl_xor(v, 1);  v += __shfl_xor(v, 2);  v += __shfl_xor(v, 4);
        v += __shfl_xor(v, 8);  v += __shfl_xor(v, 16);
        if (ks == 0) tb[p0 + i][r0 + r] = v;
      }
  }
  __syncthreads();

  // LayerNorm over r=16 + exact GELU
  if (tid < 128) {
    const int p = tid >> 4, r = tid & 15;
    float mu = 0.f;
    #pragma unroll
    for (int i = 0; i < 16; i++) mu += tb[p][i];
    mu *= (1.f / 16.f);
    float var = 0.f;
    #pragma unroll
    for (int i = 0; i < 16; i++) { float dv = tb[p][i] - mu; var += dv * dv; }
    var *= (1.f / 16.f);
    float v = (tb[p][r] - mu) * rsqrtf(var + 1e-5f) * lng[mi * 16 + r] + lnb[mi * 16 + r];
    v = 0.5f * v * (1.f + erff(v * 0.70710678118654752f));   // exact GELU
    tb2[p][r] = v;
  }
  __syncthreads();

  // phase 2: xz[p][d] = dot16(tb2[p], w2[d]); thread owns 3 d-columns, all 8 p
  {
    float acc[3][8] = {};
    #pragma unroll
    for (int rq = 0; rq < 4; rq++) {
      float4 t4[8];
      #pragma unroll
      for (int p = 0; p < 8; p++) t4[p] = *(const float4*)&tb2[p][rq * 4];
      #pragma unroll
      for (int dd = 0; dd < 3; dd++) {
        const int dcol = tid + 256 * dd;
        float4 w4 = *(const float4*)&w2s[dcol][rq * 4];
        #pragma unroll
        for (int p = 0; p < 8; p++)
          acc[dd][p] += t4[p].x * w4.x + t4[p].y * w4.y + t4[p].z * w4.z + t4[p].w * w4.w;
      }
    }
    #pragma unroll
    for (int dd = 0; dd < 3; dd++) {
      const int dcol = tid + 256 * dd;
      #pragma unroll
      for (int p = 0; p < 8; p++) {
        const int t = (l0 + p) * 4 + m;            // modality-interleaved position
        const size_t o = ((size_t)b * LM + t) * D2;
        if (dcol < D2) xr[o + dcol] = acc[dd][p];
        else           zr[o + dcol - D2] = acc[dd][p];
      }
    }
  }
}

// ---------------------------------------------------------------------------
// K2: conv_x + SiLU (on the fly) then x_dbl = xc @ x_proj_w^T (64 outs).
// grid (LM/16, B), block 256.
// ---------------------------------------------------------------------------
__global__ __launch_bounds__(256) void k2_xdbl(
    const float* __restrict__ xr, const float* __restrict__ xw,
    const float* __restrict__ cwx, float* __restrict__ xdbl)
{
  __shared__ float xcl[16][388];
  __shared__ float xws[64][388];
  const int tid = threadIdx.x;
  const int t0 = blockIdx.x * 16;
  const int b  = blockIdx.y;

  {
    const float4* p = (const float4*)xw;
    for (int i = tid; i < 64 * 96; i += 256) {
      int o = i / 96, c = (i % 96) * 4;
      *(float4*)&xws[o][c] = p[i];
    }
  }
  for (int i = tid; i < 16 * 384; i += 256) {
    const int tt = i / 384, d = i % 384;
    const int t = t0 + tt;
    const size_t base = (size_t)b * LM * D2 + d;
    float xm = (t > 0)      ? xr[base + (size_t)(t - 1) * D2] : 0.f;
    float x0 =                xr[base + (size_t)t * D2];
    float xp = (t + 1 < LM) ? xr[base + (size_t)(t + 1) * D2] : 0.f;
    float v = cwx[d * 3] * xm + cwx[d * 3 + 1] * x0 + cwx[d * 3 + 2] * xp;
    xcl[tt][d] = siluf_(v);
  }
  __syncthreads();

  {
    const int mt = tid >> 2;      // 0..63
    const int ks = tid & 3;
    const int ttg = mt >> 4;      // 0..3
    const int og = mt & 15;       // 0..15
    float acc[4][4] = {};
    for (int q = ks * 24; q < ks * 24 + 24; q++) {
      float4 a[4], w[4];
      #pragma unroll
      for (int i = 0; i < 4; i++) a[i] = *(const float4*)&xcl[ttg * 4 + i][q * 4];
      #pragma unroll
      for (int j = 0; j < 4; j++) w[j] = *(const float4*)&xws[og * 4 + j][q * 4];
      #pragma unroll
      for (int i = 0; i < 4; i++)
        #pragma unroll
        for (int j = 0; j < 4; j++)
          acc[i][j] += a[i].x * w[j].x + a[i].y * w[j].y + a[i].z * w[j].z + a[i].w * w[j].w;
    }
    #pragma unroll
    for (int i = 0; i < 4; i++)
      #pragma unroll
      for (int j = 0; j < 4; j++) {
        float v = acc[i][j];
        v += __shfl_xor(v, 1);  v += __shfl_xor(v, 2);
        acc[i][j] = v;
      }
    if (ks == 0) {
      #pragma unroll
      for (int i = 0; i < 4; i++) {
        float4 v4 = make_float4(acc[i][0], acc[i][1], acc[i][2], acc[i][3]);
        *(float4*)&xdbl[((size_t)b * LM + t0 + ttg * 4 + i) * 64 + og * 4] = v4;
      }
    }
  }
}

// ---------------------------------------------------------------------------
// K3: delta = softplus(x_dbl[:, :48] @ dt_proj_w^T + 2*dt_proj_b)
//     (bias added twice, faithful to the reference)
// grid (LM/32, B), block 256.
// ---------------------------------------------------------------------------
__global__ __launch_bounds__(256) void k3_delta(
    const float* __restrict__ xdbl, const float* __restrict__ dtw,
    const float* __restrict__ dtb, float* __restrict__ delta)
{
  __shared__ float dws[384][52];
  __shared__ float xt[32][52];
  const int tid = threadIdx.x;
  const int t0 = blockIdx.x * 32;
  const int b  = blockIdx.y;
  {
    const float4* p = (const float4*)dtw;
    for (int i = tid; i < 384 * 12; i += 256) {
      int d = i / 12, c = (i % 12) * 4;
      *(float4*)&dws[d][c] = p[i];
    }
  }
  for (int i = tid; i < 32 * 12; i += 256) {
    int tt = i / 12, c = (i % 12) * 4;
    *(float4*)&xt[tt][c] = *(const float4*)&xdbl[((size_t)b * LM + t0 + tt) * 64 + c];
  }
  __syncthreads();
  #pragma unroll
  for (int mti = 0; mti < 3; mti++) {
    const int mt = tid + 256 * mti;   // 0..767
    const int ttg = mt / 96;          // 0..7  -> 4 t each
    const int dg = mt % 96;           // 0..95 -> 4 d each
    float acc[4][4] = {};
    #pragma unroll
    for (int q = 0; q < 12; q++) {
      float4 a[4], w[4];
      #pragma unroll
      for (int i = 0; i < 4; i++) a[i] = *(const float4*)&xt[ttg * 4 + i][q * 4];
      #pragma unroll
      for (int j = 0; j < 4; j++) w[j] = *(const float4*)&dws[dg * 4 + j][q * 4];
      #pragma unroll
      for (int i = 0; i < 4; i++)
        #pragma unroll
        for (int j = 0; j < 4; j++)
          acc[i][j] += a[i].x * w[j].x + a[i].y * w[j].y + a[i].z * w[j].z + a[i].w * w[j].w;
    }
    #pragma unroll
    for (int i = 0; i < 4; i++) {
      float4 v4;
      float* vv = (float*)&v4;
      #pragma unroll
      for (int j = 0; j < 4; j++)
        vv[j] = softplusf_(acc[i][j] + 2.f * dtb[dg * 4 + j]);
      *(float4*)&delta[((size_t)b * LM + t0 + ttg * 4 + i) * D2 + dg * 4] = v4;
    }
  }
}

// ---------------------------------------------------------------------------
// S1: per-chunk scan aggregates.  Thread = d lane (coalesced), all 8 states.
// grid (NCHK, B), block 384.
// ---------------------------------------------------------------------------
__global__ __launch_bounds__(384) void s1_scan(
    const float* __restrict__ xr, const float* __restrict__ delta,
    const float* __restrict__ xdbl, const float* __restrict__ alog,
    const float* __restrict__ cwx, float* __restrict__ aP, float* __restrict__ bAg)
{
  __shared__ float Bs[TCHK][8];
  const int d = threadIdx.x;
  const int c = blockIdx.x, b = blockIdx.y;
  const int t0 = c * TCHK;
  for (int i = d; i < TCHK * 8; i += 384) {
    const int tt = i >> 3, s = i & 7;
    Bs[tt][s] = xdbl[((size_t)b * LM + t0 + tt) * 64 + 48 + s];
  }
  float a[8];
  #pragma unroll
  for (int s = 0; s < 8; s++) a[s] = -expf(alog[d * 8 + s]);
  const float w0 = cwx[d * 3], w1 = cwx[d * 3 + 1], w2 = cwx[d * 3 + 2];
  const float* xp = xr + (size_t)b * LM * D2 + d;
  const float* dp = delta + (size_t)b * LM * D2 + d;
  float xm = (t0 > 0) ? xp[(size_t)(t0 - 1) * D2] : 0.f;
  float x0 = xp[(size_t)t0 * D2];
  float h[8] = {};
  float ap[8];
  #pragma unroll
  for (int s = 0; s < 8; s++) ap[s] = 1.f;
  __syncthreads();
  for (int tt = 0; tt < TCHK; tt++) {
    const int t = t0 + tt;
    const float xn = (t + 1 < LM) ? xp[(size_t)(t + 1) * D2] : 0.f;
    const float xc = siluf_(w0 * xm + w1 * x0 + w2 * xn);
    const float dv = dp[(size_t)t * D2];
    #pragma unroll
    for (int s = 0; s < 8; s++) {
      const float dA = expf(dv * a[s]);
      ap[s] *= dA;
      h[s] = dA * h[s] + (dv * Bs[tt][s]) * xc;
    }
    xm = x0; x0 = xn;
  }
  const size_t o = (((size_t)b * NCHK + c) * 8) * D2 + d;
  #pragma unroll
  for (int s = 0; s < 8; s++) { aP[o + (size_t)s * D2] = ap[s]; bAg[o + (size_t)s * D2] = h[s]; }
}

// ---------------------------------------------------------------------------
// S2: exclusive scan over chunk aggregates -> initial h per chunk.
// 12288 threads total.
// ---------------------------------------------------------------------------
__global__ __launch_bounds__(256) void s2_combine(
    const float* __restrict__ aP, const float* __restrict__ bAg, float* __restrict__ hI)
{
  const int idx = blockIdx.x * 256 + threadIdx.x;   // 0..12287
  const int d = idx % 384;
  const int s = (idx / 384) & 7;
  const int b = idx / 3072;
  float h = 0.f;
  for (int c = 0; c < NCHK; c++) {
    const size_t o = (((size_t)b * NCHK + c) * 8 + s) * D2 + d;
    const float av = aP[o], bv = bAg[o];
    hI[o] = h;
    h = av * h + bv;
  }
}

// ---------------------------------------------------------------------------
// S3: rescan with initial h, y = h.C + D*x, RMSNorm over d, gate by
//     silu(silu(conv_z)) — the reference applies SiLU twice on the z branch.
// Writes Yg (aliases the delta buffer: every delta read precedes the write).
// grid (NCHK, B), block 384.
// ---------------------------------------------------------------------------
__global__ __launch_bounds__(384) void s3_rescan(
    const float* __restrict__ xr, const float* __restrict__ zr,
    const float* delta_in, const float* __restrict__ xdbl,
    const float* __restrict__ hI, const float* __restrict__ alog,
    const float* __restrict__ cwx, const float* __restrict__ cwz,
    const float* __restrict__ Dv, const float* __restrict__ nw,
    float* Yg)
{
  __shared__ float Bs[TCHK][8];
  __shared__ float Cs[TCHK][8];
  __shared__ float yt[TCHK][389];
  __shared__ float part[TCHK][6];
  __shared__ float rinv[TCHK];
  const int tid = threadIdx.x;
  const int d = tid;
  const int c = blockIdx.x, b = blockIdx.y;
  const int t0 = c * TCHK;
  for (int i = tid; i < TCHK * 8; i += 384) {
    const int tt = i >> 3, s = i & 7;
    const size_t o = ((size_t)b * LM + t0 + tt) * 64;
    Bs[tt][s] = xdbl[o + 48 + s];
    Cs[tt][s] = xdbl[o + 56 + s];
  }
  float a[8];
  #pragma unroll
  for (int s = 0; s < 8; s++) a[s] = -expf(alog[d * 8 + s]);
  float h[8];
  const size_t ho = (((size_t)b * NCHK + c) * 8) * D2 + d;
  #pragma unroll
  for (int s = 0; s < 8; s++) h[s] = hI[ho + (size_t)s * D2];
  const float wx0 = cwx[d * 3], wx1 = cwx[d * 3 + 1], wx2 = cwx[d * 3 + 2];
  const float Dd = Dv[d], nwd = nw[d];
  const float* xp = xr + (size_t)b * LM * D2 + d;
  const float* dp = delta_in + (size_t)b * LM * D2 + d;
  float xm = (t0 > 0) ? xp[(size_t)(t0 - 1) * D2] : 0.f;
  float x0 = xp[(size_t)t0 * D2];
  __syncthreads();
  for (int tt = 0; tt < TCHK; tt++) {
    const int t = t0 + tt;
    const float xn = (t + 1 < LM) ? xp[(size_t)(t + 1) * D2] : 0.f;
    const float xc = siluf_(wx0 * xm + wx1 * x0 + wx2 * xn);
    const float dv = dp[(size_t)t * D2];
    float yv = 0.f;
    #pragma unroll
    for (int s = 0; s < 8; s++) {
      const float dA = expf(dv * a[s]);
      h[s] = dA * h[s] + (dv * Bs[tt][s]) * xc;
      yv += h[s] * Cs[tt][s];
    }
    yv += Dd * xc;
    yt[tt][d] = yv;
    xm = x0; x0 = xn;
  }
  __syncthreads();
  {
    const int t = tid & 63, j = tid >> 6;   // 6 partials per t
    float sum = 0.f;
    #pragma unroll
    for (int k = 0; k < 64; k++) { const float v = yt[t][j * 64 + k]; sum += v * v; }
    part[t][j] = sum;
  }
  __syncthreads();
  if (tid < TCHK) {
    float sm = 0.f;
    #pragma unroll
    for (int j = 0; j < 6; j++) sm += part[tid][j];
    rinv[tid] = rsqrtf(sm * (1.f / 384.f) + 1e-5f);
  }
  __syncthreads();
  const float wz0 = cwz[d * 3], wz1 = cwz[d * 3 + 1], wz2 = cwz[d * 3 + 2];
  const float* zp = zr + (size_t)b * LM * D2 + d;
  float zm = (t0 > 0) ? zp[(size_t)(t0 - 1) * D2] : 0.f;
  float z0 = zp[(size_t)t0 * D2];
  for (int tt = 0; tt < TCHK; tt++) {
    const int t = t0 + tt;
    const float zn = (t + 1 < LM) ? zp[(size_t)(t + 1) * D2] : 0.f;
    // reference: zT = silu(conv_z(z)); gate = silu(zT)  -> SiLU applied twice
    const float zc = siluf_(siluf_(wz0 * zm + wz1 * z0 + wz2 * zn));
    Yg[((size_t)b * LM + t) * D2 + d] = yt[tt][d] * rinv[tt] * nwd * zc;
    zm = z0; z0 = zn;
  }
}

// ---------------------------------------------------------------------------
// K4: out = scale * Yg @ out_w[m]^T ; fp32 tiled GEMM 128x128, 8x8 microtile.
// grid (8 l-tiles, 6 o-tiles, B*M), block 256.
// ---------------------------------------------------------------------------
__global__ __launch_bounds__(256) void k4_outproj(
    const float* Yg, const float* __restrict__ owg,
    const int* __restrict__ midx, const float* __restrict__ scalep,
    float* __restrict__ out)
{
  __shared__ float aT[8][132];
  __shared__ float bT[8][132];
  const int tid = threadIdx.x;
  const int lt = blockIdx.x;
  const int ot = blockIdx.y;
  const int bm = blockIdx.z;
  const int b = bm >> 2, m = bm & 3;
  const int mi = midx[m];
  const int l0 = lt * 128, o0 = ot * 128;
  const float scale = scalep[0];
  const int ty = tid >> 4, tx = tid & 15;
  const int arow = tid >> 1;
  const int akq = (tid & 1) * 4;
  const float* Ab = Yg + ((size_t)b * LM + m) * D2;    // row l at + l*4*D2
  const float* Bb = owg + (size_t)mi * 768 * D2;
  float acc[8][8] = {};
  for (int k0 = 0; k0 < D2; k0 += 8) {
    float4 av = *(const float4*)&Ab[(size_t)(l0 + arow) * 4 * D2 + k0 + akq];
    float4 bv = *(const float4*)&Bb[(size_t)(o0 + arow) * D2 + k0 + akq];
    __syncthreads();
    aT[akq + 0][arow] = av.x; aT[akq + 1][arow] = av.y;
    aT[akq + 2][arow] = av.z; aT[akq + 3][arow] = av.w;
    bT[akq + 0][arow] = bv.x; bT[akq + 1][arow] = bv.y;
    bT[akq + 2][arow] = bv.z; bT[akq + 3][arow] = bv.w;
    __syncthreads();
    #pragma unroll
    for (int k = 0; k < 8; k++) {
      float4 a0 = *(const float4*)&aT[k][ty * 8];
      float4 a1 = *(const float4*)&aT[k][ty * 8 + 4];
      float4 b0 = *(const float4*)&bT[k][tx * 8];
      float4 b1 = *(const float4*)&bT[k][tx * 8 + 4];
      float ar[8] = {a0.x, a0.y, a0.z, a0.w, a1.x, a1.y, a1.z, a1.w};
      float br[8] = {b0.x, b0.y, b0.z, b0.w, b1.x, b1.y, b1.z, b1.w};
      #pragma unroll
      for (int i = 0; i < 8; i++)
        #pragma unroll
        for (int j = 0; j < 8; j++)
          acc[i][j] += ar[i] * br[j];
    }
  }
  #pragma unroll
  for (int i = 0; i < 8; i++) {
    const int l = l0 + ty * 8 + i;
    const size_t o = (((size_t)(b * 4 + m)) * 1024 + l) * 768 + o0 + tx * 8;
    float4 v0 = make_float4(acc[i][0] * scale, acc[i][1] * scale, acc[i][2] * scale, acc[i][3] * scale);
    float4 v1 = make_float4(acc[i][4] * scale, acc[i][5] * scale, acc[i][6] * scale, acc[i][7] * scale);
    *(float4*)&out[o] = v0;
    *(float4*)&out[o + 4] = v1;
  }
}

// ---------------------------------------------------------------------------
extern "C" void kernel_launch(void* const* d_in, const int* in_sizes, int n_in,
                              void* d_out, int out_size, void* d_ws, size_t ws_size,
                              hipStream_t stream)
{
  const float* hs   = (const float*)d_in[0];
  const float* w1   = (const float*)d_in[1];
  const float* lng  = (const float*)d_in[2];
  const float* lnb  = (const float*)d_in[3];
  const float* w2   = (const float*)d_in[4];
  const float* xw   = (const float*)d_in[5];
  const float* dtw  = (const float*)d_in[6];
  const float* dtb  = (const float*)d_in[7];
  const float* alog = (const float*)d_in[8];
  const float* Dv   = (const float*)d_in[9];
  const float* cwx  = (const float*)d_in[10];
  const float* cwz  = (const float*)d_in[11];
  const float* nw   = (const float*)d_in[12];
  const float* ow   = (const float*)d_in[13];
  const float* sc   = (const float*)d_in[14];
  const int*   midx = (const int*)d_in[15];
  float* out = (float*)d_out;

  float* ws = (float*)d_ws;
  const size_t NE = (size_t)4 * LM * D2;          // 6.29M floats
  float* xr    = ws;
  float* zr    = xr + NE;
  float* delta = zr + NE;                          // later reused as Yg (safe)
  float* xdbl  = delta + NE;                       // 4*4096*64
  float* aP    = xdbl + (size_t)4 * LM * 64;
  float* bAg   = aP + (size_t)4 * NCHK * 8 * D2;
  float* hI    = bAg + (size_t)4 * NCHK * 8 * D2;

  k1_inproj<<<dim3(128, 4, 4), 256, 0, stream>>>(hs, w1, lng, lnb, w2, midx, xr, zr);
  k2_xdbl<<<dim3(256, 4), 256, 0, stream>>>(xr, xw, cwx, xdbl);
  k3_delta<<<dim3(128, 4), 256, 0, stream>>>(xdbl, dtw, dtb, delta);
  s1_scan<<<dim3(NCHK, 4), 384, 0, stream>>>(xr, delta, xdbl, alog, cwx, aP, bAg);
  s2_combine<<<48, 256, 0, stream>>>(aP, bAg, hI);
  s3_rescan<<<dim3(NCHK, 4), 384, 0, stream>>>(xr, zr, delta, xdbl, hI, alog, cwx, cwz, Dv, nw, delta);
  k4_outproj<<<dim3(8, 6, 16), 256, 0, stream>>>(delta, ow, midx, sc, out);
}

// Round 3
// 566.785 us; speedup vs baseline: 1.0981x; 1.0981x over previous
//
#include <hip/hip_runtime.h>
#include <hip/hip_bf16.h>

// Problem constants (B=4, M=4, L=1024, DM=768)
#define LM   4096   // interleaved sequence length L*M
#define D2   384    // d_inner/2
#define NCHK 64     // scan chunks
#define TCHK 64     // timesteps per chunk

typedef __attribute__((ext_vector_type(8))) short short8b;   // 8 bf16 (4 VGPRs)
typedef __attribute__((ext_vector_type(4))) float f32x4;

__device__ __forceinline__ float siluf_(float x) { return x / (1.f + expf(-x)); }
__device__ __forceinline__ float softplusf_(float x) {
  return fmaxf(x, 0.f) + log1pf(expf(-fabsf(x)));
}
__device__ __forceinline__ short f2b_(float f) {
  __hip_bfloat16 h = __float2bfloat16(f);   // RNE
  return *reinterpret_cast<short*>(&h);
}

// ---------------------------------------------------------------------------
// K1: fused in-projection.  t = hidden @ w1^T -> LayerNorm -> exact GELU ->
//     xz = t @ w2^T, written modality-interleaved as x (d<384) / z (d>=384).
// grid (L/8, M, B), block 256.
// ---------------------------------------------------------------------------
__global__ __launch_bounds__(256) void k1_inproj(
    const float* __restrict__ hs, const float* __restrict__ w1g,
    const float* __restrict__ lng, const float* __restrict__ lnb,
    const float* __restrict__ w2g, const int* __restrict__ midx,
    float* __restrict__ xr, float* __restrict__ zr)
{
  __shared__ float hsl[8][772];     // 8 positions x 768 (+pad)
  __shared__ float w1s[16][772];
  __shared__ float w2s[768][20];    // 768 x 16 (+pad, keeps f4 alignment)
  __shared__ float tb[8][16];
  __shared__ float tb2[8][16];
  const int tid = threadIdx.x;
  const int l0 = blockIdx.x * 8;
  const int m  = blockIdx.y;
  const int b  = blockIdx.z;
  const int mi = midx[m];

  {
    const float4* p = (const float4*)(w1g + (size_t)mi * 16 * 768);
    for (int i = tid; i < 16 * 192; i += 256) {
      int r = i / 192, c = (i % 192) * 4;
      *(float4*)&w1s[r][c] = p[i];
    }
    const float4* q = (const float4*)(w2g + (size_t)mi * 768 * 16);
    for (int i = tid; i < 768 * 4; i += 256) {
      int dd = i / 4, c = (i % 4) * 4;
      *(float4*)&w2s[dd][c] = q[i];
    }
    const float4* hp = (const float4*)(hs + (((size_t)(b * 4 + m)) * 1024 + l0) * 768);
    for (int i = tid; i < 8 * 192; i += 256) {
      int r = i / 192, c = (i % 192) * 4;
      *(float4*)&hsl[r][c] = hp[i];
    }
  }
  __syncthreads();

  // phase 1: t[p][r] = dot768(hidden[p], w1[r]); microtile 4p x 4r, 32-way K-split
  {
    const int mt = tid >> 5;        // 0..7
    const int ks = tid & 31;
    const int p0 = (mt >> 2) * 4;   // 0,4
    const int r0 = (mt & 3) * 4;    // 0,4,8,12
    float acc[4][4] = {};
    #pragma unroll
    for (int jj = 0; jj < 6; jj++) {
      const int off = ks * 4 + jj * 128;   // spreads ks across banks
      float4 a[4], w[4];
      #pragma unroll
      for (int i = 0; i < 4; i++) a[i] = *(const float4*)&hsl[p0 + i][off];
      #pragma unroll
      for (int r = 0; r < 4; r++) w[r] = *(const float4*)&w1s[r0 + r][off];
      #pragma unroll
      for (int i = 0; i < 4; i++)
        #pragma unroll
        for (int r = 0; r < 4; r++)
          acc[i][r] += a[i].x * w[r].x + a[i].y * w[r].y + a[i].z * w[r].z + a[i].w * w[r].w;
    }
    #pragma unroll
    for (int i = 0; i < 4; i++)
      #pragma unroll
      for (int r = 0; r < 4; r++) {
        float v = acc[i][r];
        v += __shfl_xor(v, 1);  v += __shfl_xor(v, 2);  v += __shfl_xor(v, 4);
        v += __shfl_xor(v, 8);  v += __shfl_xor(v, 16);
        if (ks == 0) tb[p0 + i][r0 + r] = v;
      }
  }
  __syncthreads();

  // LayerNorm over r=16 + exact GELU
  if (tid < 128) {
    const int p = tid >> 4, r = tid & 15;
    float mu = 0.f;
    #pragma unroll
    for (int i = 0; i < 16; i++) mu += tb[p][i];
    mu *= (1.f / 16.f);
    float var = 0.f;
    #pragma unroll
    for (int i = 0; i < 16; i++) { float dv = tb[p][i] - mu; var += dv * dv; }
    var *= (1.f / 16.f);
    float v = (tb[p][r] - mu) * rsqrtf(var + 1e-5f) * lng[mi * 16 + r] + lnb[mi * 16 + r];
    v = 0.5f * v * (1.f + erff(v * 0.70710678118654752f));   // exact GELU
    tb2[p][r] = v;
  }
  __syncthreads();

  // phase 2: xz[p][d] = dot16(tb2[p], w2[d]); thread owns 3 d-columns, all 8 p
  {
    float acc[3][8] = {};
    #pragma unroll
    for (int rq = 0; rq < 4; rq++) {
      float4 t4[8];
      #pragma unroll
      for (int p = 0; p < 8; p++) t4[p] = *(const float4*)&tb2[p][rq * 4];
      #pragma unroll
      for (int dd = 0; dd < 3; dd++) {
        const int dcol = tid + 256 * dd;
        float4 w4 = *(const float4*)&w2s[dcol][rq * 4];
        #pragma unroll
        for (int p = 0; p < 8; p++)
          acc[dd][p] += t4[p].x * w4.x + t4[p].y * w4.y + t4[p].z * w4.z + t4[p].w * w4.w;
      }
    }
    #pragma unroll
    for (int dd = 0; dd < 3; dd++) {
      const int dcol = tid + 256 * dd;
      #pragma unroll
      for (int p = 0; p < 8; p++) {
        const int t = (l0 + p) * 4 + m;            // modality-interleaved position
        const size_t o = ((size_t)b * LM + t) * D2;
        if (dcol < D2) xr[o + dcol] = acc[dd][p];
        else           zr[o + dcol - D2] = acc[dd][p];
      }
    }
  }
}

// ---------------------------------------------------------------------------
// K2: conv_x + SiLU (on the fly) then x_dbl = xc @ x_proj_w^T (64 outs).
// grid (LM/16, B), block 256.
// ---------------------------------------------------------------------------
__global__ __launch_bounds__(256) void k2_xdbl(
    const float* __restrict__ xr, const float* __restrict__ xw,
    const float* __restrict__ cwx, float* __restrict__ xdbl)
{
  __shared__ float xcl[16][388];
  __shared__ float xws[64][388];
  const int tid = threadIdx.x;
  const int t0 = blockIdx.x * 16;
  const int b  = blockIdx.y;

  {
    const float4* p = (const float4*)xw;
    for (int i = tid; i < 64 * 96; i += 256) {
      int o = i / 96, c = (i % 96) * 4;
      *(float4*)&xws[o][c] = p[i];
    }
  }
  for (int i = tid; i < 16 * 384; i += 256) {
    const int tt = i / 384, d = i % 384;
    const int t = t0 + tt;
    const size_t base = (size_t)b * LM * D2 + d;
    float xm = (t > 0)      ? xr[base + (size_t)(t - 1) * D2] : 0.f;
    float x0 =                xr[base + (size_t)t * D2];
    float xp = (t + 1 < LM) ? xr[base + (size_t)(t + 1) * D2] : 0.f;
    float v = cwx[d * 3] * xm + cwx[d * 3 + 1] * x0 + cwx[d * 3 + 2] * xp;
    xcl[tt][d] = siluf_(v);
  }
  __syncthreads();

  {
    const int mt = tid >> 2;      // 0..63
    const int ks = tid & 3;
    const int ttg = mt >> 4;      // 0..3
    const int og = mt & 15;       // 0..15
    float acc[4][4] = {};
    for (int q = ks * 24; q < ks * 24 + 24; q++) {
      float4 a[4], w[4];
      #pragma unroll
      for (int i = 0; i < 4; i++) a[i] = *(const float4*)&xcl[ttg * 4 + i][q * 4];
      #pragma unroll
      for (int j = 0; j < 4; j++) w[j] = *(const float4*)&xws[og * 4 + j][q * 4];
      #pragma unroll
      for (int i = 0; i < 4; i++)
        #pragma unroll
        for (int j = 0; j < 4; j++)
          acc[i][j] += a[i].x * w[j].x + a[i].y * w[j].y + a[i].z * w[j].z + a[i].w * w[j].w;
    }
    #pragma unroll
    for (int i = 0; i < 4; i++)
      #pragma unroll
      for (int j = 0; j < 4; j++) {
        float v = acc[i][j];
        v += __shfl_xor(v, 1);  v += __shfl_xor(v, 2);
        acc[i][j] = v;
      }
    if (ks == 0) {
      #pragma unroll
      for (int i = 0; i < 4; i++) {
        float4 v4 = make_float4(acc[i][0], acc[i][1], acc[i][2], acc[i][3]);
        *(float4*)&xdbl[((size_t)b * LM + t0 + ttg * 4 + i) * 64 + og * 4] = v4;
      }
    }
  }
}

// ---------------------------------------------------------------------------
// K3: delta = softplus(x_dbl[:, :48] @ dt_proj_w^T + 2*dt_proj_b)
//     (bias added twice, faithful to the reference)
// grid (LM/32, B), block 256.
// ---------------------------------------------------------------------------
__global__ __launch_bounds__(256) void k3_delta(
    const float* __restrict__ xdbl, const float* __restrict__ dtw,
    const float* __restrict__ dtb, float* __restrict__ delta)
{
  __shared__ float dws[384][52];
  __shared__ float xt[32][52];
  const int tid = threadIdx.x;
  const int t0 = blockIdx.x * 32;
  const int b  = blockIdx.y;
  {
    const float4* p = (const float4*)dtw;
    for (int i = tid; i < 384 * 12; i += 256) {
      int d = i / 12, c = (i % 12) * 4;
      *(float4*)&dws[d][c] = p[i];
    }
  }
  for (int i = tid; i < 32 * 12; i += 256) {
    int tt = i / 12, c = (i % 12) * 4;
    *(float4*)&xt[tt][c] = *(const float4*)&xdbl[((size_t)b * LM + t0 + tt) * 64 + c];
  }
  __syncthreads();
  #pragma unroll
  for (int mti = 0; mti < 3; mti++) {
    const int mt = tid + 256 * mti;   // 0..767
    const int ttg = mt / 96;          // 0..7  -> 4 t each
    const int dg = mt % 96;           // 0..95 -> 4 d each
    float acc[4][4] = {};
    #pragma unroll
    for (int q = 0; q < 12; q++) {
      float4 a[4], w[4];
      #pragma unroll
      for (int i = 0; i < 4; i++) a[i] = *(const float4*)&xt[ttg * 4 + i][q * 4];
      #pragma unroll
      for (int j = 0; j < 4; j++) w[j] = *(const float4*)&dws[dg * 4 + j][q * 4];
      #pragma unroll
      for (int i = 0; i < 4; i++)
        #pragma unroll
        for (int j = 0; j < 4; j++)
          acc[i][j] += a[i].x * w[j].x + a[i].y * w[j].y + a[i].z * w[j].z + a[i].w * w[j].w;
    }
    #pragma unroll
    for (int i = 0; i < 4; i++) {
      float4 v4;
      float* vv = (float*)&v4;
      #pragma unroll
      for (int j = 0; j < 4; j++)
        vv[j] = softplusf_(acc[i][j] + 2.f * dtb[dg * 4 + j]);
      *(float4*)&delta[((size_t)b * LM + t0 + ttg * 4 + i) * D2 + dg * 4] = v4;
    }
  }
}

// ---------------------------------------------------------------------------
// S1: per-chunk scan aggregates.  Thread = d lane (coalesced), all 8 states.
// grid (NCHK, B), block 384.
// ---------------------------------------------------------------------------
__global__ __launch_bounds__(384) void s1_scan(
    const float* __restrict__ xr, const float* __restrict__ delta,
    const float* __restrict__ xdbl, const float* __restrict__ alog,
    const float* __restrict__ cwx, float* __restrict__ aP, float* __restrict__ bAg)
{
  __shared__ float Bs[TCHK][8];
  const int d = threadIdx.x;
  const int c = blockIdx.x, b = blockIdx.y;
  const int t0 = c * TCHK;
  for (int i = d; i < TCHK * 8; i += 384) {
    const int tt = i >> 3, s = i & 7;
    Bs[tt][s] = xdbl[((size_t)b * LM + t0 + tt) * 64 + 48 + s];
  }
  float a[8];
  #pragma unroll
  for (int s = 0; s < 8; s++) a[s] = -expf(alog[d * 8 + s]);
  const float w0 = cwx[d * 3], w1 = cwx[d * 3 + 1], w2 = cwx[d * 3 + 2];
  const float* xp = xr + (size_t)b * LM * D2 + d;
  const float* dp = delta + (size_t)b * LM * D2 + d;
  float xm = (t0 > 0) ? xp[(size_t)(t0 - 1) * D2] : 0.f;
  float x0 = xp[(size_t)t0 * D2];
  float h[8] = {};
  float ap[8];
  #pragma unroll
  for (int s = 0; s < 8; s++) ap[s] = 1.f;
  __syncthreads();
  for (int tt = 0; tt < TCHK; tt++) {
    const int t = t0 + tt;
    const float xn = (t + 1 < LM) ? xp[(size_t)(t + 1) * D2] : 0.f;
    const float xc = siluf_(w0 * xm + w1 * x0 + w2 * xn);
    const float dv = dp[(size_t)t * D2];
    #pragma unroll
    for (int s = 0; s < 8; s++) {
      const float dA = expf(dv * a[s]);
      ap[s] *= dA;
      h[s] = dA * h[s] + (dv * Bs[tt][s]) * xc;
    }
    xm = x0; x0 = xn;
  }
  const size_t o = (((size_t)b * NCHK + c) * 8) * D2 + d;
  #pragma unroll
  for (int s = 0; s < 8; s++) { aP[o + (size_t)s * D2] = ap[s]; bAg[o + (size_t)s * D2] = h[s]; }
}

// ---------------------------------------------------------------------------
// S2: exclusive scan over chunk aggregates -> initial h per chunk.
// 12288 threads total.
// ---------------------------------------------------------------------------
__global__ __launch_bounds__(256) void s2_combine(
    const float* __restrict__ aP, const float* __restrict__ bAg, float* __restrict__ hI)
{
  const int idx = blockIdx.x * 256 + threadIdx.x;   // 0..12287
  const int d = idx % 384;
  const int s = (idx / 384) & 7;
  const int b = idx / 3072;
  float h = 0.f;
  for (int c = 0; c < NCHK; c++) {
    const size_t o = (((size_t)b * NCHK + c) * 8 + s) * D2 + d;
    const float av = aP[o], bv = bAg[o];
    hI[o] = h;
    h = av * h + bv;
  }
}

// ---------------------------------------------------------------------------
// WCONV: out_w (4 x 768 x 384 fp32) -> bf16, into the dead aP region.
// grid 1152, block 256, 4 elems/thread.
// ---------------------------------------------------------------------------
__global__ __launch_bounds__(256) void wconv(
    const float* __restrict__ w, short* __restrict__ w16)
{
  const int i = (blockIdx.x * 256 + threadIdx.x) * 4;   // < 1179648
  const float4 v = *(const float4*)&w[i];
  ushort4 o;
  o.x = (unsigned short)f2b_(v.x);
  o.y = (unsigned short)f2b_(v.y);
  o.z = (unsigned short)f2b_(v.z);
  o.w = (unsigned short)f2b_(v.w);
  *(ushort4*)&w16[i] = o;
}

// ---------------------------------------------------------------------------
// S3: rescan with initial h, y = h.C + D*x, RMSNorm over d, gate by
//     silu(silu(conv_z)) — the reference applies SiLU twice on the z branch.
// Writes Yg (aliases the delta buffer: every delta read precedes the write).
// grid (NCHK, B), block 384.
// ---------------------------------------------------------------------------
__global__ __launch_bounds__(384) void s3_rescan(
    const float* __restrict__ xr, const float* __restrict__ zr,
    const float* delta_in, const float* __restrict__ xdbl,
    const float* __restrict__ hI, const float* __restrict__ alog,
    const float* __restrict__ cwx, const float* __restrict__ cwz,
    const float* __restrict__ Dv, const float* __restrict__ nw,
    float* Yg)
{
  __shared__ float Bs[TCHK][8];
  __shared__ float Cs[TCHK][8];
  __shared__ float yt[TCHK][389];
  __shared__ float part[TCHK][6];
  __shared__ float rinv[TCHK];
  const int tid = threadIdx.x;
  const int d = tid;
  const int c = blockIdx.x, b = blockIdx.y;
  const int t0 = c * TCHK;
  for (int i = tid; i < TCHK * 8; i += 384) {
    const int tt = i >> 3, s = i & 7;
    const size_t o = ((size_t)b * LM + t0 + tt) * 64;
    Bs[tt][s] = xdbl[o + 48 + s];
    Cs[tt][s] = xdbl[o + 56 + s];
  }
  float a[8];
  #pragma unroll
  for (int s = 0; s < 8; s++) a[s] = -expf(alog[d * 8 + s]);
  float h[8];
  const size_t ho = (((size_t)b * NCHK + c) * 8) * D2 + d;
  #pragma unroll
  for (int s = 0; s < 8; s++) h[s] = hI[ho + (size_t)s * D2];
  const float wx0 = cwx[d * 3], wx1 = cwx[d * 3 + 1], wx2 = cwx[d * 3 + 2];
  const float Dd = Dv[d], nwd = nw[d];
  const float* xp = xr + (size_t)b * LM * D2 + d;
  const float* dp = delta_in + (size_t)b * LM * D2 + d;
  float xm = (t0 > 0) ? xp[(size_t)(t0 - 1) * D2] : 0.f;
  float x0 = xp[(size_t)t0 * D2];
  __syncthreads();
  for (int tt = 0; tt < TCHK; tt++) {
    const int t = t0 + tt;
    const float xn = (t + 1 < LM) ? xp[(size_t)(t + 1) * D2] : 0.f;
    const float xc = siluf_(wx0 * xm + wx1 * x0 + wx2 * xn);
    const float dv = dp[(size_t)t * D2];
    float yv = 0.f;
    #pragma unroll
    for (int s = 0; s < 8; s++) {
      const float dA = expf(dv * a[s]);
      h[s] = dA * h[s] + (dv * Bs[tt][s]) * xc;
      yv += h[s] * Cs[tt][s];
    }
    yv += Dd * xc;
    yt[tt][d] = yv;
    xm = x0; x0 = xn;
  }
  __syncthreads();
  {
    const int t = tid & 63, j = tid >> 6;   // 6 partials per t
    float sum = 0.f;
    #pragma unroll
    for (int k = 0; k < 64; k++) { const float v = yt[t][j * 64 + k]; sum += v * v; }
    part[t][j] = sum;
  }
  __syncthreads();
  if (tid < TCHK) {
    float sm = 0.f;
    #pragma unroll
    for (int j = 0; j < 6; j++) sm += part[tid][j];
    rinv[tid] = rsqrtf(sm * (1.f / 384.f) + 1e-5f);
  }
  __syncthreads();
  const float wz0 = cwz[d * 3], wz1 = cwz[d * 3 + 1], wz2 = cwz[d * 3 + 2];
  const float* zp = zr + (size_t)b * LM * D2 + d;
  float zm = (t0 > 0) ? zp[(size_t)(t0 - 1) * D2] : 0.f;
  float z0 = zp[(size_t)t0 * D2];
  for (int tt = 0; tt < TCHK; tt++) {
    const int t = t0 + tt;
    const float zn = (t + 1 < LM) ? zp[(size_t)(t + 1) * D2] : 0.f;
    // reference: zT = silu(conv_z(z)); gate = silu(zT)  -> SiLU applied twice
    const float zc = siluf_(siluf_(wz0 * zm + wz1 * z0 + wz2 * zn));
    Yg[((size_t)b * LM + t) * D2 + d] = yt[tt][d] * rinv[tt] * nwd * zc;
    zm = z0; z0 = zn;
  }
}

// ---------------------------------------------------------------------------
// K4 (MFMA): out = scale * Yg @ out_w[m]^T via mfma_f32_16x16x32_bf16.
// LDS-free: A (Yg fp32, cvt in-reg) and B (bf16 weights) read per-lane from
// global; both are L2/L3-resident.  128x128 tile, 4 waves x (64x64 quadrant),
// 4x4 fragment repeats, K=384 in 12 steps of 32.
// A-frag: lane holds A[lane%16][k0 + (lane/16)*8 + i], i=0..7 (contiguous).
// B-frag: lane holds B[k0 + (lane/16)*8 + i][lane%16] = W[col][k] (contiguous).
// C/D  : col = lane&15, row = (lane>>4)*4 + reg   [verified mapping]
// grid (8, 6, 16), block 256.
// ---------------------------------------------------------------------------
__global__ __launch_bounds__(256) void k4_mfma(
    const float* __restrict__ Yg, const short* __restrict__ W16,
    const int* __restrict__ midx, const float* __restrict__ scalep,
    float* __restrict__ out)
{
  const int tid = threadIdx.x;
  const int wid = tid >> 6, lane = tid & 63;
  const int lt = blockIdx.x, ot = blockIdx.y, bm = blockIdx.z;
  const int b = bm >> 2, m = bm & 3;
  const int mi = midx[m];
  const int l0 = lt * 128, o0 = ot * 128;
  const int wr = wid >> 1, wc = wid & 1;        // 64x64 quadrant per wave
  const int lr = lane & 15, lg = lane >> 4;     // frag row / k-group
  const float scale = scalep[0];

  const float* Ab = Yg + (size_t)b * LM * D2;             // row l at t=l*4+m
  const short* Bb = W16 + (size_t)mi * 768 * D2;

  f32x4 acc[4][4];
  #pragma unroll
  for (int i = 0; i < 4; i++)
    #pragma unroll
    for (int j = 0; j < 4; j++) acc[i][j] = (f32x4){0.f, 0.f, 0.f, 0.f};

  for (int k0 = 0; k0 < D2; k0 += 32) {
    const int kk = k0 + lg * 8;
    short8b afr[4], bfr[4];
    #pragma unroll
    for (int mr = 0; mr < 4; mr++) {
      const int row = l0 + wr * 64 + mr * 16 + lr;
      const float* ap = Ab + (size_t)(row * 4 + m) * D2 + kk;
      const f32x4 a0 = *(const f32x4*)ap;
      const f32x4 a1 = *(const f32x4*)(ap + 4);
      short8b af;
      af[0] = f2b_(a0.x); af[1] = f2b_(a0.y); af[2] = f2b_(a0.z); af[3] = f2b_(a0.w);
      af[4] = f2b_(a1.x); af[5] = f2b_(a1.y); af[6] = f2b_(a1.z); af[7] = f2b_(a1.w);
      afr[mr] = af;
    }
    #pragma unroll
    for (int nr = 0; nr < 4; nr++) {
      const int col = o0 + wc * 64 + nr * 16 + lr;
      bfr[nr] = *(const short8b*)(Bb + (size_t)col * D2 + kk);
    }
    #pragma unroll
    for (int mr = 0; mr < 4; mr++)
      #pragma unroll
      for (int nr = 0; nr < 4; nr++)
        acc[mr][nr] = __builtin_amdgcn_mfma_f32_16x16x32_bf16(
            afr[mr], bfr[nr], acc[mr][nr], 0, 0, 0);
  }

  // epilogue: C[row][col], col = lane&15, row = (lane>>4)*4 + r
  #pragma unroll
  for (int mr = 0; mr < 4; mr++) {
    #pragma unroll
    for (int r = 0; r < 4; r++) {
      const int row = l0 + wr * 64 + mr * 16 + lg * 4 + r;
      const size_t ob = (((size_t)(b * 4 + m)) * 1024 + row) * 768;
      #pragma unroll
      for (int nr = 0; nr < 4; nr++) {
        const int col = o0 + wc * 64 + nr * 16 + lr;
        out[ob + col] = acc[mr][nr][r] * scale;
      }
    }
  }
}

// ---------------------------------------------------------------------------
extern "C" void kernel_launch(void* const* d_in, const int* in_sizes, int n_in,
                              void* d_out, int out_size, void* d_ws, size_t ws_size,
                              hipStream_t stream)
{
  const float* hs   = (const float*)d_in[0];
  const float* w1   = (const float*)d_in[1];
  const float* lng  = (const float*)d_in[2];
  const float* lnb  = (const float*)d_in[3];
  const float* w2   = (const float*)d_in[4];
  const float* xw   = (const float*)d_in[5];
  const float* dtw  = (const float*)d_in[6];
  const float* dtb  = (const float*)d_in[7];
  const float* alog = (const float*)d_in[8];
  const float* Dv   = (const float*)d_in[9];
  const float* cwx  = (const float*)d_in[10];
  const float* cwz  = (const float*)d_in[11];
  const float* nw   = (const float*)d_in[12];
  const float* ow   = (const float*)d_in[13];
  const float* sc   = (const float*)d_in[14];
  const int*   midx = (const int*)d_in[15];
  float* out = (float*)d_out;

  float* ws = (float*)d_ws;
  const size_t NE = (size_t)4 * LM * D2;          // 6.29M floats
  float* xr    = ws;
  float* zr    = xr + NE;
  float* delta = zr + NE;                          // later reused as Yg (safe)
  float* xdbl  = delta + NE;                       // 4*4096*64
  float* aP    = xdbl + (size_t)4 * LM * 64;
  float* bAg   = aP + (size_t)4 * NCHK * 8 * D2;
  float* hI    = bAg + (size_t)4 * NCHK * 8 * D2;
  short* owb16 = (short*)aP;                       // aP dead after s2: 2.36MB <= 3.14MB

  k1_inproj<<<dim3(128, 4, 4), 256, 0, stream>>>(hs, w1, lng, lnb, w2, midx, xr, zr);
  k2_xdbl<<<dim3(256, 4), 256, 0, stream>>>(xr, xw, cwx, xdbl);
  k3_delta<<<dim3(128, 4), 256, 0, stream>>>(xdbl, dtw, dtb, delta);
  s1_scan<<<dim3(NCHK, 4), 384, 0, stream>>>(xr, delta, xdbl, alog, cwx, aP, bAg);
  s2_combine<<<48, 256, 0, stream>>>(aP, bAg, hI);
  wconv<<<1152, 256, 0, stream>>>(ow, owb16);      // after s2 (aP no longer read)
  s3_rescan<<<dim3(NCHK, 4), 384, 0, stream>>>(xr, zr, delta, xdbl, hI, alog, cwx, cwz, Dv, nw, delta);
  k4_mfma<<<dim3(8, 6, 16), 256, 0, stream>>>(delta, owb16, midx, sc, out);
}

// Round 4
// 462.577 us; speedup vs baseline: 1.3455x; 1.2253x over previous
//
#include <hip/hip_runtime.h>
#include <hip/hip_bf16.h>

// Problem constants (B=4, M=4, L=1024, DM=768)
#define LM   4096   // interleaved sequence length L*M
#define D2   384    // d_inner/2
#define NCHK 64     // scan chunks
#define TCHK 64     // timesteps per chunk

typedef __attribute__((ext_vector_type(8))) short short8b;   // 8 bf16 (4 VGPRs)
typedef __attribute__((ext_vector_type(4))) float f32x4;

__device__ __forceinline__ float siluf_(float x) { return x / (1.f + expf(-x)); }
__device__ __forceinline__ float softplusf_(float x) {
  return fmaxf(x, 0.f) + log1pf(expf(-fabsf(x)));
}
__device__ __forceinline__ short f2b_(float f) {
  __hip_bfloat16 h = __float2bfloat16(f);   // RNE
  return *reinterpret_cast<short*>(&h);
}

// ---------------------------------------------------------------------------
// K1a: t = GELU(LN(hidden @ w1^T)).  Thread = (pos, r): full 768-dot, LN via
// 16-lane shuffle group.  LDS = w1 only (49 KB -> 3 blocks/CU).
// grid (L/16, M, B) = (64,4,4), block 256.
// ---------------------------------------------------------------------------
__global__ __launch_bounds__(256) void k1a_proj(
    const float* __restrict__ hs, const float* __restrict__ w1g,
    const float* __restrict__ lng, const float* __restrict__ lnb,
    const int* __restrict__ midx, float* __restrict__ tbuf)
{
  __shared__ float w1s[16][772];
  const int tid = threadIdx.x;
  const int l0 = blockIdx.x * 16;
  const int m  = blockIdx.y;
  const int b  = blockIdx.z;
  const int mi = midx[m];
  {
    const float4* wp = (const float4*)(w1g + (size_t)mi * 16 * 768);
    for (int i = tid; i < 16 * 192; i += 256) {
      int r = i / 192, c = (i % 192) * 4;
      *(float4*)&w1s[r][c] = wp[i];
    }
  }
  __syncthreads();
  const int p = tid >> 4, r = tid & 15;
  const float* hrow = hs + (((size_t)(b * 4 + m)) * 1024 + l0 + p) * 768;
  float a0 = 0.f, a1 = 0.f, a2 = 0.f, a3 = 0.f;   // break the FMA chain
  #pragma unroll 4
  for (int k = 0; k < 192; k += 4) {
    float4 x0 = *(const float4*)&hrow[(k + 0) * 4];
    float4 x1 = *(const float4*)&hrow[(k + 1) * 4];
    float4 x2 = *(const float4*)&hrow[(k + 2) * 4];
    float4 x3 = *(const float4*)&hrow[(k + 3) * 4];
    float4 w0 = *(const float4*)&w1s[r][(k + 0) * 4];
    float4 w1 = *(const float4*)&w1s[r][(k + 1) * 4];
    float4 w2 = *(const float4*)&w1s[r][(k + 2) * 4];
    float4 w3 = *(const float4*)&w1s[r][(k + 3) * 4];
    a0 += x0.x*w0.x + x0.y*w0.y + x0.z*w0.z + x0.w*w0.w;
    a1 += x1.x*w1.x + x1.y*w1.y + x1.z*w1.z + x1.w*w1.w;
    a2 += x2.x*w2.x + x2.y*w2.y + x2.z*w2.z + x2.w*w2.w;
    a3 += x3.x*w3.x + x3.y*w3.y + x3.z*w3.z + x3.w*w3.w;
  }
  const float acc = (a0 + a1) + (a2 + a3);
  // LayerNorm over the 16-lane r-group
  float s = acc, q = acc * acc;
  #pragma unroll
  for (int msk = 1; msk < 16; msk <<= 1) {
    s += __shfl_xor(s, msk);
    q += __shfl_xor(q, msk);
  }
  const float mu  = s * (1.f / 16.f);
  const float var = q * (1.f / 16.f) - mu * mu;
  float v = (acc - mu) * rsqrtf(var + 1e-5f) * lng[mi * 16 + r] + lnb[mi * 16 + r];
  v = 0.5f * v * (1.f + erff(v * 0.70710678118654752f));   // exact GELU
  tbuf[(((size_t)(b * 4 + m)) * 1024 + l0 + p) * 16 + r] = v;
}

// ---------------------------------------------------------------------------
// K1b: xz = t @ w2^T, written modality-interleaved into xr/zr.  Thread owns
// 3 d-columns with w2 in registers; t-tile (2 KB) in LDS.
// grid (L/32, M, B) = (32,4,4), block 256.
// ---------------------------------------------------------------------------
__global__ __launch_bounds__(256) void k1b_xz(
    const float* __restrict__ tbuf, const float* __restrict__ w2g,
    const int* __restrict__ midx,
    float* __restrict__ xr, float* __restrict__ zr)
{
  __shared__ float ts[32][16];
  const int tid = threadIdx.x;
  const int l0 = blockIdx.x * 32;
  const int m  = blockIdx.y;
  const int b  = blockIdx.z;
  const int mi = midx[m];
  if (tid < 128) {
    float4 v = *(const float4*)&tbuf[(((size_t)(b * 4 + m)) * 1024 + l0) * 16 + tid * 4];
    *(float4*)&ts[tid >> 2][(tid & 3) * 4] = v;
  }
  float w2c[3][16];
  #pragma unroll
  for (int dd = 0; dd < 3; dd++) {
    const int d = tid + 256 * dd;
    #pragma unroll
    for (int rq = 0; rq < 4; rq++)
      *(float4*)&w2c[dd][rq * 4] = *(const float4*)&w2g[((size_t)mi * 768 + d) * 16 + rq * 4];
  }
  __syncthreads();
  for (int p = 0; p < 32; p++) {
    float tv[16];
    #pragma unroll
    for (int rq = 0; rq < 4; rq++) *(float4*)&tv[rq * 4] = *(const float4*)&ts[p][rq * 4];
    const int t = (l0 + p) * 4 + m;
    const size_t o = ((size_t)b * LM + t) * D2;
    #pragma unroll
    for (int dd = 0; dd < 3; dd++) {
      float a = 0.f;
      #pragma unroll
      for (int r2 = 0; r2 < 16; r2++) a += tv[r2] * w2c[dd][r2];
      const int d = tid + 256 * dd;
      if (d < D2) xr[o + d] = a;
      else        zr[o + d - D2] = a;
    }
  }
}

// ---------------------------------------------------------------------------
// K2: conv_x + SiLU (on the fly) then x_dbl = xc @ x_proj_w^T (64 outs).
// Weights staged in two 32-row passes -> LDS 74 KB -> 2 blocks/CU.
// grid (LM/16, B), block 256.
// ---------------------------------------------------------------------------
__global__ __launch_bounds__(256) void k2_xdbl(
    const float* __restrict__ xr, const float* __restrict__ xw,
    const float* __restrict__ cwx, float* __restrict__ xdbl)
{
  __shared__ float xcl[16][388];
  __shared__ float xws[32][388];
  const int tid = threadIdx.x;
  const int t0 = blockIdx.x * 16;
  const int b  = blockIdx.y;

  for (int i = tid; i < 16 * 384; i += 256) {
    const int tt = i / 384, d = i % 384;
    const int t = t0 + tt;
    const size_t base = (size_t)b * LM * D2 + d;
    float xm = (t > 0)      ? xr[base + (size_t)(t - 1) * D2] : 0.f;
    float x0 =                xr[base + (size_t)t * D2];
    float xp = (t + 1 < LM) ? xr[base + (size_t)(t + 1) * D2] : 0.f;
    float v = cwx[d * 3] * xm + cwx[d * 3 + 1] * x0 + cwx[d * 3 + 2] * xp;
    xcl[tt][d] = siluf_(v);
  }

  #pragma unroll
  for (int pass = 0; pass < 2; pass++) {
    if (pass) __syncthreads();          // drain pass-0 compute before xws reuse
    {
      const float4* wp = (const float4*)(xw + (size_t)pass * 32 * 384);
      for (int i = tid; i < 32 * 96; i += 256) {
        int o = i / 96, c = (i % 96) * 4;
        *(float4*)&xws[o][c] = wp[i];
      }
    }
    __syncthreads();
    const int ks  = tid & 3;
    const int mt  = tid >> 2;      // 0..63
    const int og4 = mt & 7;        // 8 output quads -> 32 outputs this pass
    const int ttg = mt >> 3;       // 0..7 -> 2 t each
    float acc[2][4] = {};
    for (int q = ks * 24; q < ks * 24 + 24; q++) {
      float4 a[2], w[4];
      #pragma unroll
      for (int i = 0; i < 2; i++) a[i] = *(const float4*)&xcl[ttg * 2 + i][q * 4];
      #pragma unroll
      for (int j = 0; j < 4; j++) w[j] = *(const float4*)&xws[og4 * 4 + j][q * 4];
      #pragma unroll
      for (int i = 0; i < 2; i++)
        #pragma unroll
        for (int j = 0; j < 4; j++)
          acc[i][j] += a[i].x * w[j].x + a[i].y * w[j].y + a[i].z * w[j].z + a[i].w * w[j].w;
    }
    #pragma unroll
    for (int i = 0; i < 2; i++)
      #pragma unroll
      for (int j = 0; j < 4; j++) {
        float v = acc[i][j];
        v += __shfl_xor(v, 1);  v += __shfl_xor(v, 2);
        acc[i][j] = v;
      }
    if (ks == 0) {
      #pragma unroll
      for (int i = 0; i < 2; i++) {
        float4 v4 = make_float4(acc[i][0], acc[i][1], acc[i][2], acc[i][3]);
        *(float4*)&xdbl[((size_t)b * LM + t0 + ttg * 2 + i) * 64 + pass * 32 + og4 * 4] = v4;
      }
    }
  }
}

// ---------------------------------------------------------------------------
// K3: delta = softplus(x_dbl[:, :48] @ dt_proj_w^T + 2*dt_proj_b)
//     (bias added twice, faithful to the reference).  Thread-per-d, weights
//     in registers, 6 KB LDS.
// grid (LM/32, B), block 384.
// ---------------------------------------------------------------------------
__global__ __launch_bounds__(384) void k3_delta(
    const float* __restrict__ xdbl, const float* __restrict__ dtw,
    const float* __restrict__ dtb, float* __restrict__ delta)
{
  __shared__ float xt[32][48];
  const int tid = threadIdx.x;     // = d
  const int t0 = blockIdx.x * 32;
  const int b  = blockIdx.y;
  for (int i = tid; i < 32 * 12; i += 384) {
    int tt = i / 12, c = (i % 12) * 4;
    *(float4*)&xt[tt][c] = *(const float4*)&xdbl[((size_t)b * LM + t0 + tt) * 64 + c];
  }
  float wc[48];
  #pragma unroll
  for (int rq = 0; rq < 12; rq++)
    *(float4*)&wc[rq * 4] = *(const float4*)&dtw[(size_t)tid * 48 + rq * 4];
  const float bias2 = 2.f * dtb[tid];
  __syncthreads();
  for (int p = 0; p < 32; p++) {
    float acc = 0.f;
    #pragma unroll
    for (int r2 = 0; r2 < 48; r2++) acc += xt[p][r2] * wc[r2];
    delta[((size_t)b * LM + t0 + p) * D2 + tid] = softplusf_(acc + bias2);
  }
}

// ---------------------------------------------------------------------------
// S1: per-chunk scan aggregates.  768 threads: (d, state-half) -> 12 waves/CU.
// grid (NCHK, B), block 768.
// ---------------------------------------------------------------------------
__global__ __launch_bounds__(768) void s1_scan(
    const float* __restrict__ xr, const float* __restrict__ delta,
    const float* __restrict__ xdbl, const float* __restrict__ alog,
    const float* __restrict__ cwx, float* __restrict__ aP, float* __restrict__ bAg)
{
  __shared__ float Bs[TCHK][8];
  const int tid = threadIdx.x;
  const int half = tid >= 384 ? 1 : 0;
  const int d = tid - half * 384;
  const int c = blockIdx.x, b = blockIdx.y;
  const int t0 = c * TCHK;
  for (int i = tid; i < TCHK * 8; i += 768) {
    const int tt = i >> 3, s = i & 7;
    Bs[tt][s] = xdbl[((size_t)b * LM + t0 + tt) * 64 + 48 + s];
  }
  float a[4];
  #pragma unroll
  for (int s = 0; s < 4; s++) a[s] = -expf(alog[d * 8 + half * 4 + s]);
  const float w0 = cwx[d * 3], w1 = cwx[d * 3 + 1], w2 = cwx[d * 3 + 2];
  const float* xp = xr + (size_t)b * LM * D2 + d;
  const float* dp = delta + (size_t)b * LM * D2 + d;
  float xm = (t0 > 0) ? xp[(size_t)(t0 - 1) * D2] : 0.f;
  float x0 = xp[(size_t)t0 * D2];
  float h[4] = {};
  float ap[4] = {1.f, 1.f, 1.f, 1.f};
  __syncthreads();
  for (int tt = 0; tt < TCHK; tt++) {
    const int t = t0 + tt;
    const float xn = (t + 1 < LM) ? xp[(size_t)(t + 1) * D2] : 0.f;
    const float xc = siluf_(w0 * xm + w1 * x0 + w2 * xn);
    const float dv = dp[(size_t)t * D2];
    #pragma unroll
    for (int s = 0; s < 4; s++) {
      const float dA = expf(dv * a[s]);
      ap[s] *= dA;
      h[s] = dA * h[s] + (dv * Bs[tt][half * 4 + s]) * xc;
    }
    xm = x0; x0 = xn;
  }
  const size_t o = (((size_t)b * NCHK + c) * 8 + half * 4) * D2 + d;
  #pragma unroll
  for (int s = 0; s < 4; s++) { aP[o + (size_t)s * D2] = ap[s]; bAg[o + (size_t)s * D2] = h[s]; }
}

// ---------------------------------------------------------------------------
// S2: exclusive scan over chunk aggregates -> initial h per chunk.
// ---------------------------------------------------------------------------
__global__ __launch_bounds__(256) void s2_combine(
    const float* __restrict__ aP, const float* __restrict__ bAg, float* __restrict__ hI)
{
  const int idx = blockIdx.x * 256 + threadIdx.x;   // 0..12287
  const int d = idx % 384;
  const int s = (idx / 384) & 7;
  const int b = idx / 3072;
  float h = 0.f;
  for (int c = 0; c < NCHK; c++) {
    const size_t o = (((size_t)b * NCHK + c) * 8 + s) * D2 + d;
    const float av = aP[o], bv = bAg[o];
    hI[o] = h;
    h = av * h + bv;
  }
}

// ---------------------------------------------------------------------------
// WCONV: out_w (4 x 768 x 384 fp32) -> bf16, into the dead aP region.
// ---------------------------------------------------------------------------
__global__ __launch_bounds__(256) void wconv(
    const float* __restrict__ w, short* __restrict__ w16)
{
  const int i = (blockIdx.x * 256 + threadIdx.x) * 4;   // < 1179648
  const float4 v = *(const float4*)&w[i];
  ushort4 o;
  o.x = (unsigned short)f2b_(v.x);
  o.y = (unsigned short)f2b_(v.y);
  o.z = (unsigned short)f2b_(v.z);
  o.w = (unsigned short)f2b_(v.w);
  *(ushort4*)&w16[i] = o;
}

// ---------------------------------------------------------------------------
// S3: rescan + y + RMSNorm + silu(silu(conv_z)) gate.  The 64-step chunk is
// processed in two 32-row halves so yt LDS halves: 56 KB -> 2 blocks/CU.
// Writes Yg (aliases delta: reads of a row precede its write).
// grid (NCHK, B), block 384.
// ---------------------------------------------------------------------------
__global__ __launch_bounds__(384) void s3_rescan(
    const float* __restrict__ xr, const float* __restrict__ zr,
    const float* delta_in, const float* __restrict__ xdbl,
    const float* __restrict__ hI, const float* __restrict__ alog,
    const float* __restrict__ cwx, const float* __restrict__ cwz,
    const float* __restrict__ Dv, const float* __restrict__ nw,
    float* Yg)
{
  __shared__ float Bs[TCHK][8];
  __shared__ float Cs[TCHK][8];
  __shared__ float yt[32][389];
  __shared__ float part[32][12];
  __shared__ float rinv[32];
  const int tid = threadIdx.x;
  const int d = tid;
  const int c = blockIdx.x, b = blockIdx.y;
  const int t0 = c * TCHK;
  for (int i = tid; i < TCHK * 8; i += 384) {
    const int tt = i >> 3, s = i & 7;
    const size_t o = ((size_t)b * LM + t0 + tt) * 64;
    Bs[tt][s] = xdbl[o + 48 + s];
    Cs[tt][s] = xdbl[o + 56 + s];
  }
  float a[8];
  #pragma unroll
  for (int s = 0; s < 8; s++) a[s] = -expf(alog[d * 8 + s]);
  float h[8];
  const size_t ho = (((size_t)b * NCHK + c) * 8) * D2 + d;
  #pragma unroll
  for (int s = 0; s < 8; s++) h[s] = hI[ho + (size_t)s * D2];
  const float wx0 = cwx[d * 3], wx1 = cwx[d * 3 + 1], wx2 = cwx[d * 3 + 2];
  const float wz0 = cwz[d * 3], wz1 = cwz[d * 3 + 1], wz2 = cwz[d * 3 + 2];
  const float Dd = Dv[d], nwd = nw[d];
  const float* xp = xr + (size_t)b * LM * D2 + d;
  const float* zp = zr + (size_t)b * LM * D2 + d;
  const float* dp = delta_in + (size_t)b * LM * D2 + d;
  float xm = (t0 > 0) ? xp[(size_t)(t0 - 1) * D2] : 0.f;
  float x0 = xp[(size_t)t0 * D2];
  float zm = (t0 > 0) ? zp[(size_t)(t0 - 1) * D2] : 0.f;
  float z0 = zp[(size_t)t0 * D2];
  __syncthreads();

  #pragma unroll
  for (int H = 0; H < 2; H++) {
    const int tb = t0 + H * 32;
    // scan 32 steps
    for (int tt = 0; tt < 32; tt++) {
      const int t = tb + tt;
      const float xn = (t + 1 < LM) ? xp[(size_t)(t + 1) * D2] : 0.f;
      const float xc = siluf_(wx0 * xm + wx1 * x0 + wx2 * xn);
      const float dv = dp[(size_t)t * D2];
      float yv = 0.f;
      #pragma unroll
      for (int s = 0; s < 8; s++) {
        const float dA = expf(dv * a[s]);
        h[s] = dA * h[s] + (dv * Bs[H * 32 + tt][s]) * xc;
        yv += h[s] * Cs[H * 32 + tt][s];
      }
      yv += Dd * xc;
      yt[tt][d] = yv;
      xm = x0; x0 = xn;
    }
    __syncthreads();
    // RMS partials: 32 rows x 12 k-groups
    {
      const int tr = tid & 31, j = tid >> 5;   // j 0..11
      float sum = 0.f;
      #pragma unroll
      for (int k = 0; k < 32; k++) { const float v = yt[tr][j * 32 + k]; sum += v * v; }
      part[tr][j] = sum;
    }
    __syncthreads();
    if (tid < 32) {
      float sm = 0.f;
      #pragma unroll
      for (int j = 0; j < 12; j++) sm += part[tid][j];
      rinv[tid] = rsqrtf(sm * (1.f / 384.f) + 1e-5f);
    }
    __syncthreads();
    // gate + write 32 rows
    for (int tt = 0; tt < 32; tt++) {
      const int t = tb + tt;
      const float zn = (t + 1 < LM) ? zp[(size_t)(t + 1) * D2] : 0.f;
      // reference: zT = silu(conv_z(z)); gate = silu(zT) -> SiLU twice
      const float zc = siluf_(siluf_(wz0 * zm + wz1 * z0 + wz2 * zn));
      Yg[((size_t)b * LM + t) * D2 + d] = yt[tt][d] * rinv[tt] * nwd * zc;
      zm = z0; z0 = zn;
    }
    __syncthreads();   // yt reuse barrier
  }
}

// ---------------------------------------------------------------------------
// K4 (MFMA): out = scale * Yg @ out_w[m]^T via mfma_f32_16x16x32_bf16.
// grid (8, 6, 16), block 256.
// ---------------------------------------------------------------------------
__global__ __launch_bounds__(256) void k4_mfma(
    const float* __restrict__ Yg, const short* __restrict__ W16,
    const int* __restrict__ midx, const float* __restrict__ scalep,
    float* __restrict__ out)
{
  const int tid = threadIdx.x;
  const int wid = tid >> 6, lane = tid & 63;
  const int lt = blockIdx.x, ot = blockIdx.y, bm = blockIdx.z;
  const int b = bm >> 2, m = bm & 3;
  const int mi = midx[m];
  const int l0 = lt * 128, o0 = ot * 128;
  const int wr = wid >> 1, wc = wid & 1;        // 64x64 quadrant per wave
  const int lr = lane & 15, lg = lane >> 4;     // frag row / k-group
  const float scale = scalep[0];

  const float* Ab = Yg + (size_t)b * LM * D2;             // row l at t=l*4+m
  const short* Bb = W16 + (size_t)mi * 768 * D2;

  f32x4 acc[4][4];
  #pragma unroll
  for (int i = 0; i < 4; i++)
    #pragma unroll
    for (int j = 0; j < 4; j++) acc[i][j] = (f32x4){0.f, 0.f, 0.f, 0.f};

  for (int k0 = 0; k0 < D2; k0 += 32) {
    const int kk = k0 + lg * 8;
    short8b afr[4], bfr[4];
    #pragma unroll
    for (int mr = 0; mr < 4; mr++) {
      const int row = l0 + wr * 64 + mr * 16 + lr;
      const float* ap = Ab + (size_t)(row * 4 + m) * D2 + kk;
      const f32x4 a0 = *(const f32x4*)ap;
      const f32x4 a1 = *(const f32x4*)(ap + 4);
      short8b af;
      af[0] = f2b_(a0.x); af[1] = f2b_(a0.y); af[2] = f2b_(a0.z); af[3] = f2b_(a0.w);
      af[4] = f2b_(a1.x); af[5] = f2b_(a1.y); af[6] = f2b_(a1.z); af[7] = f2b_(a1.w);
      afr[mr] = af;
    }
    #pragma unroll
    for (int nr = 0; nr < 4; nr++) {
      const int col = o0 + wc * 64 + nr * 16 + lr;
      bfr[nr] = *(const short8b*)(Bb + (size_t)col * D2 + kk);
    }
    #pragma unroll
    for (int mr = 0; mr < 4; mr++)
      #pragma unroll
      for (int nr = 0; nr < 4; nr++)
        acc[mr][nr] = __builtin_amdgcn_mfma_f32_16x16x32_bf16(
            afr[mr], bfr[nr], acc[mr][nr], 0, 0, 0);
  }

  #pragma unroll
  for (int mr = 0; mr < 4; mr++) {
    #pragma unroll
    for (int r = 0; r < 4; r++) {
      const int row = l0 + wr * 64 + mr * 16 + lg * 4 + r;
      const size_t ob = (((size_t)(b * 4 + m)) * 1024 + row) * 768;
      #pragma unroll
      for (int nr = 0; nr < 4; nr++) {
        const int col = o0 + wc * 64 + nr * 16 + lr;
        out[ob + col] = acc[mr][nr][r] * scale;
      }
    }
  }
}

// ---------------------------------------------------------------------------
extern "C" void kernel_launch(void* const* d_in, const int* in_sizes, int n_in,
                              void* d_out, int out_size, void* d_ws, size_t ws_size,
                              hipStream_t stream)
{
  const float* hs   = (const float*)d_in[0];
  const float* w1   = (const float*)d_in[1];
  const float* lng  = (const float*)d_in[2];
  const float* lnb  = (const float*)d_in[3];
  const float* w2   = (const float*)d_in[4];
  const float* xw   = (const float*)d_in[5];
  const float* dtw  = (const float*)d_in[6];
  const float* dtb  = (const float*)d_in[7];
  const float* alog = (const float*)d_in[8];
  const float* Dv   = (const float*)d_in[9];
  const float* cwx  = (const float*)d_in[10];
  const float* cwz  = (const float*)d_in[11];
  const float* nw   = (const float*)d_in[12];
  const float* ow   = (const float*)d_in[13];
  const float* sc   = (const float*)d_in[14];
  const int*   midx = (const int*)d_in[15];
  float* out = (float*)d_out;

  float* ws = (float*)d_ws;
  const size_t NE = (size_t)4 * LM * D2;          // 6.29M floats
  float* xr    = ws;
  float* zr    = xr + NE;
  float* delta = zr + NE;                          // later reused as Yg (safe)
  float* xdbl  = delta + NE;                       // 4*4096*64
  float* aP    = xdbl + (size_t)4 * LM * 64;
  float* bAg   = aP + (size_t)4 * NCHK * 8 * D2;
  float* hI    = bAg + (size_t)4 * NCHK * 8 * D2;
  float* tbuf  = aP;                               // k1 intermediate: dead before s1
  short* owb16 = (short*)aP;                       // aP dead after s2

  k1a_proj<<<dim3(64, 4, 4), 256, 0, stream>>>(hs, w1, lng, lnb, midx, tbuf);
  k1b_xz<<<dim3(32, 4, 4), 256, 0, stream>>>(tbuf, w2, midx, xr, zr);
  k2_xdbl<<<dim3(256, 4), 256, 0, stream>>>(xr, xw, cwx, xdbl);
  k3_delta<<<dim3(128, 4), 384, 0, stream>>>(xdbl, dtw, dtb, delta);
  s1_scan<<<dim3(NCHK, 4), 768, 0, stream>>>(xr, delta, xdbl, alog, cwx, aP, bAg);
  s2_combine<<<48, 256, 0, stream>>>(aP, bAg, hI);
  wconv<<<1152, 256, 0, stream>>>(ow, owb16);      // after s2 (aP no longer read)
  s3_rescan<<<dim3(NCHK, 4), 384, 0, stream>>>(xr, zr, delta, xdbl, hI, alog, cwx, cwz, Dv, nw, delta);
  k4_mfma<<<dim3(8, 6, 16), 256, 0, stream>>>(delta, owb16, midx, sc, out);
}

// Round 8
// 425.171 us; speedup vs baseline: 1.4639x; 1.0880x over previous
//
#include <hip/hip_runtime.h>
#include <hip/hip_bf16.h>

// Problem constants (B=4, M=4, L=1024, DM=768)
#define LM    4096   // interleaved sequence length L*M
#define D2    384    // d_inner/2
#define NCHK2 128    // scan chunks
#define TC2   32     // timesteps per chunk

typedef __attribute__((ext_vector_type(8))) short short8b;   // 8 bf16 (4 VGPRs)
typedef __attribute__((ext_vector_type(4))) float f32x4;

__device__ __forceinline__ float siluf_(float x) { return x / (1.f + expf(-x)); }
__device__ __forceinline__ float softplusf_(float x) {
  return fmaxf(x, 0.f) + log1pf(expf(-fabsf(x)));
}
__device__ __forceinline__ short f2b_(float f) {
  __hip_bfloat16 h = __float2bfloat16(f);   // RNE
  return *reinterpret_cast<short*>(&h);
}

// ---------------------------------------------------------------------------
// K1a: t = GELU(LN(hidden @ w1^T)).  Thread = (pos, r): full 768-dot, LN via
// 16-lane shuffle group.  LDS = w1 only (49 KB -> 3 blocks/CU).
// grid (L/16, M, B) = (64,4,4), block 256.
// ---------------------------------------------------------------------------
__global__ __launch_bounds__(256) void k1a_proj(
    const float* __restrict__ hs, const float* __restrict__ w1g,
    const float* __restrict__ lng, const float* __restrict__ lnb,
    const int* __restrict__ midx, float* __restrict__ tbuf)
{
  __shared__ float w1s[16][772];
  const int tid = threadIdx.x;
  const int l0 = blockIdx.x * 16;
  const int m  = blockIdx.y;
  const int b  = blockIdx.z;
  const int mi = midx[m];
  {
    const float4* wp = (const float4*)(w1g + (size_t)mi * 16 * 768);
    for (int i = tid; i < 16 * 192; i += 256) {
      int r = i / 192, c = (i % 192) * 4;
      *(float4*)&w1s[r][c] = wp[i];
    }
  }
  __syncthreads();
  const int p = tid >> 4, r = tid & 15;
  const float* hrow = hs + (((size_t)(b * 4 + m)) * 1024 + l0 + p) * 768;
  float a0 = 0.f, a1 = 0.f, a2 = 0.f, a3 = 0.f;   // break the FMA chain
  #pragma unroll 4
  for (int k = 0; k < 192; k += 4) {
    float4 x0 = *(const float4*)&hrow[(k + 0) * 4];
    float4 x1 = *(const float4*)&hrow[(k + 1) * 4];
    float4 x2 = *(const float4*)&hrow[(k + 2) * 4];
    float4 x3 = *(const float4*)&hrow[(k + 3) * 4];
    float4 w0 = *(const float4*)&w1s[r][(k + 0) * 4];
    float4 w1 = *(const float4*)&w1s[r][(k + 1) * 4];
    float4 w2 = *(const float4*)&w1s[r][(k + 2) * 4];
    float4 w3 = *(const float4*)&w1s[r][(k + 3) * 4];
    a0 += x0.x*w0.x + x0.y*w0.y + x0.z*w0.z + x0.w*w0.w;
    a1 += x1.x*w1.x + x1.y*w1.y + x1.z*w1.z + x1.w*w1.w;
    a2 += x2.x*w2.x + x2.y*w2.y + x2.z*w2.z + x2.w*w2.w;
    a3 += x3.x*w3.x + x3.y*w3.y + x3.z*w3.z + x3.w*w3.w;
  }
  const float acc = (a0 + a1) + (a2 + a3);
  // LayerNorm over the 16-lane r-group
  float s = acc, q = acc * acc;
  #pragma unroll
  for (int msk = 1; msk < 16; msk <<= 1) {
    s += __shfl_xor(s, msk);
    q += __shfl_xor(q, msk);
  }
  const float mu  = s * (1.f / 16.f);
  const float var = q * (1.f / 16.f) - mu * mu;
  float v = (acc - mu) * rsqrtf(var + 1e-5f) * lng[mi * 16 + r] + lnb[mi * 16 + r];
  v = 0.5f * v * (1.f + erff(v * 0.70710678118654752f));   // exact GELU
  tbuf[(((size_t)(b * 4 + m)) * 1024 + l0 + p) * 16 + r] = v;
}

// ---------------------------------------------------------------------------
// K1b: xz = t @ w2^T, written modality-interleaved into xr/zr.  Thread owns
// 3 d-columns with w2 in registers; t-tile (2 KB) in LDS.
// grid (L/32, M, B) = (32,4,4), block 256.
// ---------------------------------------------------------------------------
__global__ __launch_bounds__(256) void k1b_xz(
    const float* __restrict__ tbuf, const float* __restrict__ w2g,
    const int* __restrict__ midx,
    float* __restrict__ xr, float* __restrict__ zr)
{
  __shared__ float ts[32][16];
  const int tid = threadIdx.x;
  const int l0 = blockIdx.x * 32;
  const int m  = blockIdx.y;
  const int b  = blockIdx.z;
  const int mi = midx[m];
  if (tid < 128) {
    float4 v = *(const float4*)&tbuf[(((size_t)(b * 4 + m)) * 1024 + l0) * 16 + tid * 4];
    *(float4*)&ts[tid >> 2][(tid & 3) * 4] = v;
  }
  float w2c[3][16];
  #pragma unroll
  for (int dd = 0; dd < 3; dd++) {
    const int d = tid + 256 * dd;
    #pragma unroll
    for (int rq = 0; rq < 4; rq++)
      *(float4*)&w2c[dd][rq * 4] = *(const float4*)&w2g[((size_t)mi * 768 + d) * 16 + rq * 4];
  }
  __syncthreads();
  for (int p = 0; p < 32; p++) {
    float tv[16];
    #pragma unroll
    for (int rq = 0; rq < 4; rq++) *(float4*)&tv[rq * 4] = *(const float4*)&ts[p][rq * 4];
    const int t = (l0 + p) * 4 + m;
    const size_t o = ((size_t)b * LM + t) * D2;
    #pragma unroll
    for (int dd = 0; dd < 3; dd++) {
      float a = 0.f;
      #pragma unroll
      for (int r2 = 0; r2 < 16; r2++) a += tv[r2] * w2c[dd][r2];
      const int d = tid + 256 * dd;
      if (d < D2) xr[o + d] = a;
      else        zr[o + d - D2] = a;
    }
  }
}

// ---------------------------------------------------------------------------
// K2: conv_x + SiLU (on the fly) then x_dbl = xc @ x_proj_w^T (64 outs).
// Weights staged in two 32-row passes -> LDS 74 KB -> 2 blocks/CU.
// grid (LM/16, B), block 256.
// ---------------------------------------------------------------------------
__global__ __launch_bounds__(256) void k2_xdbl(
    const float* __restrict__ xr, const float* __restrict__ xw,
    const float* __restrict__ cwx, float* __restrict__ xdbl)
{
  __shared__ float xcl[16][388];
  __shared__ float xws[32][388];
  const int tid = threadIdx.x;
  const int t0 = blockIdx.x * 16;
  const int b  = blockIdx.y;

  for (int i = tid; i < 16 * 384; i += 256) {
    const int tt = i / 384, d = i % 384;
    const int t = t0 + tt;
    const size_t base = (size_t)b * LM * D2 + d;
    float xm = (t > 0)      ? xr[base + (size_t)(t - 1) * D2] : 0.f;
    float x0 =                xr[base + (size_t)t * D2];
    float xp = (t + 1 < LM) ? xr[base + (size_t)(t + 1) * D2] : 0.f;
    float v = cwx[d * 3] * xm + cwx[d * 3 + 1] * x0 + cwx[d * 3 + 2] * xp;
    xcl[tt][d] = siluf_(v);
  }

  #pragma unroll
  for (int pass = 0; pass < 2; pass++) {
    if (pass) __syncthreads();          // drain pass-0 compute before xws reuse
    {
      const float4* wp = (const float4*)(xw + (size_t)pass * 32 * 384);
      for (int i = tid; i < 32 * 96; i += 256) {
        int o = i / 96, c = (i % 96) * 4;
        *(float4*)&xws[o][c] = wp[i];
      }
    }
    __syncthreads();
    const int ks  = tid & 3;
    const int mt  = tid >> 2;      // 0..63
    const int og4 = mt & 7;        // 8 output quads -> 32 outputs this pass
    const int ttg = mt >> 3;       // 0..7 -> 2 t each
    float acc[2][4] = {};
    for (int q = ks * 24; q < ks * 24 + 24; q++) {
      float4 a[2], w[4];
      #pragma unroll
      for (int i = 0; i < 2; i++) a[i] = *(const float4*)&xcl[ttg * 2 + i][q * 4];
      #pragma unroll
      for (int j = 0; j < 4; j++) w[j] = *(const float4*)&xws[og4 * 4 + j][q * 4];
      #pragma unroll
      for (int i = 0; i < 2; i++)
        #pragma unroll
        for (int j = 0; j < 4; j++)
          acc[i][j] += a[i].x * w[j].x + a[i].y * w[j].y + a[i].z * w[j].z + a[i].w * w[j].w;
    }
    #pragma unroll
    for (int i = 0; i < 2; i++)
      #pragma unroll
      for (int j = 0; j < 4; j++) {
        float v = acc[i][j];
        v += __shfl_xor(v, 1);  v += __shfl_xor(v, 2);
        acc[i][j] = v;
      }
    if (ks == 0) {
      #pragma unroll
      for (int i = 0; i < 2; i++) {
        float4 v4 = make_float4(acc[i][0], acc[i][1], acc[i][2], acc[i][3]);
        *(float4*)&xdbl[((size_t)b * LM + t0 + ttg * 2 + i) * 64 + pass * 32 + og4 * 4] = v4;
      }
    }
  }
}

// ---------------------------------------------------------------------------
// K3: delta = softplus(x_dbl[:, :48] @ dt_proj_w^T + 2*dt_proj_b)
//     (bias added twice, faithful to the reference).  Thread-per-d, weights
//     in registers, 6 KB LDS.
// grid (LM/32, B), block 384.
// ---------------------------------------------------------------------------
__global__ __launch_bounds__(384) void k3_delta(
    const float* __restrict__ xdbl, const float* __restrict__ dtw,
    const float* __restrict__ dtb, float* __restrict__ delta)
{
  __shared__ float xt[32][48];
  const int tid = threadIdx.x;     // = d
  const int t0 = blockIdx.x * 32;
  const int b  = blockIdx.y;
  for (int i = tid; i < 32 * 12; i += 384) {
    int tt = i / 12, c = (i % 12) * 4;
    *(float4*)&xt[tt][c] = *(const float4*)&xdbl[((size_t)b * LM + t0 + tt) * 64 + c];
  }
  float wc[48];
  #pragma unroll
  for (int rq = 0; rq < 12; rq++)
    *(float4*)&wc[rq * 4] = *(const float4*)&dtw[(size_t)tid * 48 + rq * 4];
  const float bias2 = 2.f * dtb[tid];
  __syncthreads();
  for (int p = 0; p < 32; p++) {
    float acc = 0.f;
    #pragma unroll
    for (int r2 = 0; r2 < 48; r2++) acc += xt[p][r2] * wc[r2];
    delta[((size_t)b * LM + t0 + p) * D2 + tid] = softplusf_(acc + bias2);
  }
}

// ---------------------------------------------------------------------------
// S1: per-chunk scan aggregates.  768 threads: (d, state-half).
// A_log = log(1..8) in practice -> dA[s] = q^(s+1), one exp (runtime-checked).
// grid (NCHK2, B) = (128,4) -> 2 blocks/CU, 24 waves/CU.
// ---------------------------------------------------------------------------
__global__ __launch_bounds__(768) void s1_scan(
    const float* __restrict__ xr, const float* __restrict__ delta,
    const float* __restrict__ xdbl, const float* __restrict__ alog,
    const float* __restrict__ cwx, float* __restrict__ aP, float* __restrict__ bAg)
{
  __shared__ float Bs[TC2][8];
  const int tid = threadIdx.x;
  const int half = tid >= 384 ? 1 : 0;   // wave-uniform (384 = 6 waves)
  const int d = tid - half * 384;
  const int c = blockIdx.x, b = blockIdx.y;
  const int t0 = c * TC2;
  if (tid < TC2 * 8) {
    const int tt = tid >> 3, s = tid & 7;
    Bs[tt][s] = xdbl[((size_t)b * LM + t0 + tt) * 64 + 48 + s];
  }
  const float a1 = -expf(alog[d * 8]);     // s=0 rate
  float a[4];
  bool geo = true;
  #pragma unroll
  for (int s = 0; s < 4; s++) {
    a[s] = -expf(alog[d * 8 + half * 4 + s]);
    const float ex = (float)(half * 4 + s + 1) * a1;
    geo = geo && (fabsf(a[s] - ex) <= 1e-4f * fabsf(a[s]));
  }
  const float w0 = cwx[d * 3], w1 = cwx[d * 3 + 1], w2 = cwx[d * 3 + 2];
  const float* xp = xr + (size_t)b * LM * D2 + d;
  const float* dp = delta + (size_t)b * LM * D2 + d;
  float xm = (t0 > 0) ? xp[(size_t)(t0 - 1) * D2] : 0.f;
  float x0 = xp[(size_t)t0 * D2];
  float h[4] = {};
  float ap[4] = {1.f, 1.f, 1.f, 1.f};
  __syncthreads();
  #pragma unroll 4
  for (int tt = 0; tt < TC2; tt++) {
    const int t = t0 + tt;
    const float xn = (t + 1 < LM) ? xp[(size_t)(t + 1) * D2] : 0.f;
    const float xc = siluf_(w0 * xm + w1 * x0 + w2 * xn);
    const float dv = dp[(size_t)t * D2];
    float dA[4];
    if (geo) {
      const float q = expf(dv * a1);
      const float q2 = q * q, q4 = q2 * q2;
      if (half == 0) { dA[0] = q;      dA[1] = q2;      dA[2] = q2 * q;      dA[3] = q4; }
      else           { dA[0] = q4 * q; dA[1] = q4 * q2; dA[2] = q4 * q2 * q; dA[3] = q4 * q4; }
    } else {
      #pragma unroll
      for (int s = 0; s < 4; s++) dA[s] = expf(dv * a[s]);
    }
    const float dx = dv * xc;
    #pragma unroll
    for (int s = 0; s < 4; s++) {
      ap[s] *= dA[s];
      h[s] = dA[s] * h[s] + dx * Bs[tt][half * 4 + s];
    }
    xm = x0; x0 = xn;
  }
  const size_t o = (((size_t)b * NCHK2 + c) * 8 + half * 4) * D2 + d;
  #pragma unroll
  for (int s = 0; s < 4; s++) { aP[o + (size_t)s * D2] = ap[s]; bAg[o + (size_t)s * D2] = h[s]; }
}

// ---------------------------------------------------------------------------
// S2: exclusive scan over chunk aggregates -> initial h per chunk, written
// IN PLACE over aP.  12288 threads.
// ---------------------------------------------------------------------------
__global__ __launch_bounds__(256) void s2_combine(
    float* __restrict__ aP, const float* __restrict__ bAg)
{
  const int idx = blockIdx.x * 256 + threadIdx.x;   // 0..12287
  const int d = idx % 384;
  const int s = (idx / 384) & 7;
  const int b = idx / 3072;
  float h = 0.f;
  #pragma unroll 4
  for (int c = 0; c < NCHK2; c++) {
    const size_t o = (((size_t)b * NCHK2 + c) * 8 + s) * D2 + d;
    const float av = aP[o], bv = bAg[o];
    aP[o] = h;                     // hI
    h = av * h + bv;
  }
}

// ---------------------------------------------------------------------------
// WCONV: out_w (4 x 768 x 384 fp32) -> bf16 (aliases dead tbuf region).
// ---------------------------------------------------------------------------
__global__ __launch_bounds__(256) void wconv(
    const float* __restrict__ w, short* __restrict__ w16)
{
  const int i = (blockIdx.x * 256 + threadIdx.x) * 4;   // < 1179648
  const float4 v = *(const float4*)&w[i];
  ushort4 o;
  o.x = (unsigned short)f2b_(v.x);
  o.y = (unsigned short)f2b_(v.y);
  o.z = (unsigned short)f2b_(v.z);
  o.w = (unsigned short)f2b_(v.w);
  *(ushort4*)&w16[i] = o;
}

// ---------------------------------------------------------------------------
// S3: rescan + y + RMSNorm + silu(silu(conv_z)) gate.  32-step chunks;
// LDS ~52 KB -> 2 blocks/CU.  Writes Yg (aliases delta; per-row reads of
// delta precede the row's write).
// grid (NCHK2, B), block 384.
// ---------------------------------------------------------------------------
__global__ __launch_bounds__(384) void s3_rescan(
    const float* __restrict__ xr, const float* __restrict__ zr,
    const float* delta_in, const float* __restrict__ xdbl,
    const float* __restrict__ hI, const float* __restrict__ alog,
    const float* __restrict__ cwx, const float* __restrict__ cwz,
    const float* __restrict__ Dv, const float* __restrict__ nw,
    float* Yg)
{
  __shared__ float Bs[TC2][8];
  __shared__ float Cs[TC2][8];
  __shared__ float yt[TC2][389];
  __shared__ float part[TC2][12];
  __shared__ float rinv[TC2];
  const int tid = threadIdx.x;
  const int d = tid;
  const int c = blockIdx.x, b = blockIdx.y;
  const int t0 = c * TC2;
  if (tid < TC2 * 8) {
    const int tt = tid >> 3, s = tid & 7;
    const size_t o = ((size_t)b * LM + t0 + tt) * 64;
    Bs[tt][s] = xdbl[o + 48 + s];
    Cs[tt][s] = xdbl[o + 56 + s];
  }
  const float a1 = -expf(alog[d * 8]);
  float a[8];
  bool geo = true;
  #pragma unroll
  for (int s = 0; s < 8; s++) {
    a[s] = -expf(alog[d * 8 + s]);
    const float ex = (float)(s + 1) * a1;
    geo = geo && (fabsf(a[s] - ex) <= 1e-4f * fabsf(a[s]));
  }
  float h[8];
  const size_t ho = (((size_t)b * NCHK2 + c) * 8) * D2 + d;
  #pragma unroll
  for (int s = 0; s < 8; s++) h[s] = hI[ho + (size_t)s * D2];
  const float wx0 = cwx[d * 3], wx1 = cwx[d * 3 + 1], wx2 = cwx[d * 3 + 2];
  const float wz0 = cwz[d * 3], wz1 = cwz[d * 3 + 1], wz2 = cwz[d * 3 + 2];
  const float Dd = Dv[d], nwd = nw[d];
  const float* xp = xr + (size_t)b * LM * D2 + d;
  const float* zp = zr + (size_t)b * LM * D2 + d;
  const float* dp = delta_in + (size_t)b * LM * D2 + d;
  float xm = (t0 > 0) ? xp[(size_t)(t0 - 1) * D2] : 0.f;
  float x0 = xp[(size_t)t0 * D2];
  __syncthreads();

  #pragma unroll 4
  for (int tt = 0; tt < TC2; tt++) {
    const int t = t0 + tt;
    const float xn = (t + 1 < LM) ? xp[(size_t)(t + 1) * D2] : 0.f;
    const float xc = siluf_(wx0 * xm + wx1 * x0 + wx2 * xn);
    const float dv = dp[(size_t)t * D2];
    float dA[8];
    if (geo) {
      const float q = expf(dv * a1);
      const float q2 = q * q, q4 = q2 * q2;
      dA[0] = q;      dA[1] = q2;      dA[2] = q2 * q;      dA[3] = q4;
      dA[4] = q4 * q; dA[5] = q4 * q2; dA[6] = q4 * q2 * q; dA[7] = q4 * q4;
    } else {
      #pragma unroll
      for (int s = 0; s < 8; s++) dA[s] = expf(dv * a[s]);
    }
    const float dx = dv * xc;
    float yv = 0.f;
    #pragma unroll
    for (int s = 0; s < 8; s++) {
      h[s] = dA[s] * h[s] + dx * Bs[tt][s];
      yv += h[s] * Cs[tt][s];
    }
    yv += Dd * xc;
    yt[tt][d] = yv;
    xm = x0; x0 = xn;
  }
  __syncthreads();
  {
    const int tr = tid & 31, j = tid >> 5;   // 12 k-groups of 32
    float sum = 0.f;
    #pragma unroll
    for (int k = 0; k < 32; k++) { const float v = yt[tr][j * 32 + k]; sum += v * v; }
    part[tr][j] = sum;
  }
  __syncthreads();
  if (tid < TC2) {
    float sm = 0.f;
    #pragma unroll
    for (int j = 0; j < 12; j++) sm += part[tid][j];
    rinv[tid] = rsqrtf(sm * (1.f / 384.f) + 1e-5f);
  }
  __syncthreads();
  float zm = (t0 > 0) ? zp[(size_t)(t0 - 1) * D2] : 0.f;
  float z0 = zp[(size_t)t0 * D2];
  #pragma unroll 4
  for (int tt = 0; tt < TC2; tt++) {
    const int t = t0 + tt;
    const float zn = (t + 1 < LM) ? zp[(size_t)(t + 1) * D2] : 0.f;
    // reference: zT = silu(conv_z(z)); gate = silu(zT) -> SiLU twice
    const float zc = siluf_(siluf_(wz0 * zm + wz1 * z0 + wz2 * zn));
    Yg[((size_t)b * LM + t) * D2 + d] = yt[tt][d] * rinv[tt] * nwd * zc;
    zm = z0; z0 = zn;
  }
}

// ---------------------------------------------------------------------------
// K4 (MFMA): out = scale * Yg @ out_w[m]^T via mfma_f32_16x16x32_bf16.
// grid (8, 6, 16), block 256.
// ---------------------------------------------------------------------------
__global__ __launch_bounds__(256) void k4_mfma(
    const float* __restrict__ Yg, const short* __restrict__ W16,
    const int* __restrict__ midx, const float* __restrict__ scalep,
    float* __restrict__ out)
{
  const int tid = threadIdx.x;
  const int wid = tid >> 6, lane = tid & 63;
  const int lt = blockIdx.x, ot = blockIdx.y, bm = blockIdx.z;
  const int b = bm >> 2, m = bm & 3;
  const int mi = midx[m];
  const int l0 = lt * 128, o0 = ot * 128;
  const int wr = wid >> 1, wc = wid & 1;        // 64x64 quadrant per wave
  const int lr = lane & 15, lg = lane >> 4;     // frag row / k-group
  const float scale = scalep[0];

  const float* Ab = Yg + (size_t)b * LM * D2;             // row l at t=l*4+m
  const short* Bb = W16 + (size_t)mi * 768 * D2;

  f32x4 acc[4][4];
  #pragma unroll
  for (int i = 0; i < 4; i++)
    #pragma unroll
    for (int j = 0; j < 4; j++) acc[i][j] = (f32x4){0.f, 0.f, 0.f, 0.f};

  for (int k0 = 0; k0 < D2; k0 += 32) {
    const int kk = k0 + lg * 8;
    short8b afr[4], bfr[4];
    #pragma unroll
    for (int mr = 0; mr < 4; mr++) {
      const int row = l0 + wr * 64 + mr * 16 + lr;
      const float* ap = Ab + (size_t)(row * 4 + m) * D2 + kk;
      const f32x4 a0 = *(const f32x4*)ap;
      const f32x4 a1 = *(const f32x4*)(ap + 4);
      short8b af;
      af[0] = f2b_(a0.x); af[1] = f2b_(a0.y); af[2] = f2b_(a0.z); af[3] = f2b_(a0.w);
      af[4] = f2b_(a1.x); af[5] = f2b_(a1.y); af[6] = f2b_(a1.z); af[7] = f2b_(a1.w);
      afr[mr] = af;
    }
    #pragma unroll
    for (int nr = 0; nr < 4; nr++) {
      const int col = o0 + wc * 64 + nr * 16 + lr;
      bfr[nr] = *(const short8b*)(Bb + (size_t)col * D2 + kk);
    }
    #pragma unroll
    for (int mr = 0; mr < 4; mr++)
      #pragma unroll
      for (int nr = 0; nr < 4; nr++)
        acc[mr][nr] = __builtin_amdgcn_mfma_f32_16x16x32_bf16(
            afr[mr], bfr[nr], acc[mr][nr], 0, 0, 0);
  }

  #pragma unroll
  for (int mr = 0; mr < 4; mr++) {
    #pragma unroll
    for (int r = 0; r < 4; r++) {
      const int row = l0 + wr * 64 + mr * 16 + lg * 4 + r;
      const size_t ob = (((size_t)(b * 4 + m)) * 1024 + row) * 768;
      #pragma unroll
      for (int nr = 0; nr < 4; nr++) {
        const int col = o0 + wc * 64 + nr * 16 + lr;
        out[ob + col] = acc[mr][nr][r] * scale;
      }
    }
  }
}

// ---------------------------------------------------------------------------
extern "C" void kernel_launch(void* const* d_in, const int* in_sizes, int n_in,
                              void* d_out, int out_size, void* d_ws, size_t ws_size,
                              hipStream_t stream)
{
  const float* hs   = (const float*)d_in[0];
  const float* w1   = (const float*)d_in[1];
  const float* lng  = (const float*)d_in[2];
  const float* lnb  = (const float*)d_in[3];
  const float* w2   = (const float*)d_in[4];
  const float* xw   = (const float*)d_in[5];
  const float* dtw  = (const float*)d_in[6];
  const float* dtb  = (const float*)d_in[7];
  const float* alog = (const float*)d_in[8];
  const float* Dv   = (const float*)d_in[9];
  const float* cwx  = (const float*)d_in[10];
  const float* cwz  = (const float*)d_in[11];
  const float* nw   = (const float*)d_in[12];
  const float* ow   = (const float*)d_in[13];
  const float* sc   = (const float*)d_in[14];
  const int*   midx = (const int*)d_in[15];
  float* out = (float*)d_out;

  float* ws = (float*)d_ws;
  const size_t NE = (size_t)4 * LM * D2;          // 6.29M floats
  float* xr    = ws;
  float* zr    = xr + NE;
  float* delta = zr + NE;                          // later reused as Yg (safe)
  float* xdbl  = delta + NE;                       // 4*4096*64 = 1.05M floats
  float* tbuf  = xdbl + (size_t)4 * LM * 64;       // k1 intermediate, 1.05M floats
  short* owb16 = (short*)tbuf;                     // tbuf dead after k1b

  // chunk aggregates live in d_out (50 MB; fully rewritten by k4 at the end):
  float* aP  = out;                                // 4*128*8*384 = 1.57M floats
  float* bAg = aP + (size_t)4 * NCHK2 * 8 * D2;    // another 1.57M floats
  float* hI  = aP;                                 // s2 writes hI in place

  k1a_proj<<<dim3(64, 4, 4), 256, 0, stream>>>(hs, w1, lng, lnb, midx, tbuf);
  k1b_xz<<<dim3(32, 4, 4), 256, 0, stream>>>(tbuf, w2, midx, xr, zr);
  k2_xdbl<<<dim3(256, 4), 256, 0, stream>>>(xr, xw, cwx, xdbl);
  k3_delta<<<dim3(128, 4), 384, 0, stream>>>(xdbl, dtw, dtb, delta);
  s1_scan<<<dim3(NCHK2, 4), 768, 0, stream>>>(xr, delta, xdbl, alog, cwx, aP, bAg);
  s2_combine<<<48, 256, 0, stream>>>(aP, bAg);
  wconv<<<1152, 256, 0, stream>>>(ow, owb16);      // after k1b (tbuf dead)
  s3_rescan<<<dim3(NCHK2, 4), 384, 0, stream>>>(xr, zr, delta, xdbl, hI, alog, cwx, cwz, Dv, nw, delta);
  k4_mfma<<<dim3(8, 6, 16), 256, 0, stream>>>(delta, owb16, midx, sc, out);
}

// Round 9
// 404.933 us; speedup vs baseline: 1.5371x; 1.0500x over previous
//
#include <hip/hip_runtime.h>
#include <hip/hip_bf16.h>

// Problem constants (B=4, M=4, L=1024, DM=768)
#define LM    4096   // interleaved sequence length L*M
#define D2    384    // d_inner/2
#define NCHK2 128    // scan chunks
#define TC2   32     // timesteps per chunk

typedef __attribute__((ext_vector_type(8))) short short8b;   // 8 bf16 (4 VGPRs)
typedef __attribute__((ext_vector_type(4))) float f32x4;

__device__ __forceinline__ float siluf_(float x) { return x / (1.f + expf(-x)); }
__device__ __forceinline__ float softplusf_(float x) {
  return fmaxf(x, 0.f) + log1pf(expf(-fabsf(x)));
}
__device__ __forceinline__ short f2b_(float f) {
  __hip_bfloat16 h = __float2bfloat16(f);   // RNE
  return *reinterpret_cast<short*>(&h);
}

// ---------------------------------------------------------------------------
// K1a: t = GELU(LN(hidden @ w1^T)).  Thread = (pos, r): full 768-dot, LN via
// 16-lane shuffle group.  LDS = w1 only (49 KB -> 3 blocks/CU).
// grid (L/16, M, B) = (64,4,4), block 256.
// ---------------------------------------------------------------------------
__global__ __launch_bounds__(256) void k1a_proj(
    const float* __restrict__ hs, const float* __restrict__ w1g,
    const float* __restrict__ lng, const float* __restrict__ lnb,
    const int* __restrict__ midx, float* __restrict__ tbuf)
{
  __shared__ float w1s[16][772];
  const int tid = threadIdx.x;
  const int l0 = blockIdx.x * 16;
  const int m  = blockIdx.y;
  const int b  = blockIdx.z;
  const int mi = midx[m];
  {
    const float4* wp = (const float4*)(w1g + (size_t)mi * 16 * 768);
    for (int i = tid; i < 16 * 192; i += 256) {
      int r = i / 192, c = (i % 192) * 4;
      *(float4*)&w1s[r][c] = wp[i];
    }
  }
  __syncthreads();
  const int p = tid >> 4, r = tid & 15;
  const float* hrow = hs + (((size_t)(b * 4 + m)) * 1024 + l0 + p) * 768;
  float a0 = 0.f, a1 = 0.f, a2 = 0.f, a3 = 0.f;   // break the FMA chain
  #pragma unroll 4
  for (int k = 0; k < 192; k += 4) {
    float4 x0 = *(const float4*)&hrow[(k + 0) * 4];
    float4 x1 = *(const float4*)&hrow[(k + 1) * 4];
    float4 x2 = *(const float4*)&hrow[(k + 2) * 4];
    float4 x3 = *(const float4*)&hrow[(k + 3) * 4];
    float4 w0 = *(const float4*)&w1s[r][(k + 0) * 4];
    float4 w1 = *(const float4*)&w1s[r][(k + 1) * 4];
    float4 w2 = *(const float4*)&w1s[r][(k + 2) * 4];
    float4 w3 = *(const float4*)&w1s[r][(k + 3) * 4];
    a0 += x0.x*w0.x + x0.y*w0.y + x0.z*w0.z + x0.w*w0.w;
    a1 += x1.x*w1.x + x1.y*w1.y + x1.z*w1.z + x1.w*w1.w;
    a2 += x2.x*w2.x + x2.y*w2.y + x2.z*w2.z + x2.w*w2.w;
    a3 += x3.x*w3.x + x3.y*w3.y + x3.z*w3.z + x3.w*w3.w;
  }
  const float acc = (a0 + a1) + (a2 + a3);
  // LayerNorm over the 16-lane r-group
  float s = acc, q = acc * acc;
  #pragma unroll
  for (int msk = 1; msk < 16; msk <<= 1) {
    s += __shfl_xor(s, msk);
    q += __shfl_xor(q, msk);
  }
  const float mu  = s * (1.f / 16.f);
  const float var = q * (1.f / 16.f) - mu * mu;
  float v = (acc - mu) * rsqrtf(var + 1e-5f) * lng[mi * 16 + r] + lnb[mi * 16 + r];
  v = 0.5f * v * (1.f + erff(v * 0.70710678118654752f));   // exact GELU
  tbuf[(((size_t)(b * 4 + m)) * 1024 + l0 + p) * 16 + r] = v;
}

// ---------------------------------------------------------------------------
// K1b: xz = t @ w2^T, written modality-interleaved into xr/zr.  Thread owns
// 3 d-columns with w2 in registers; t-tile (2 KB) in LDS.
// grid (L/32, M, B) = (32,4,4), block 256.
// ---------------------------------------------------------------------------
__global__ __launch_bounds__(256) void k1b_xz(
    const float* __restrict__ tbuf, const float* __restrict__ w2g,
    const int* __restrict__ midx,
    float* __restrict__ xr, float* __restrict__ zr)
{
  __shared__ float ts[32][16];
  const int tid = threadIdx.x;
  const int l0 = blockIdx.x * 32;
  const int m  = blockIdx.y;
  const int b  = blockIdx.z;
  const int mi = midx[m];
  if (tid < 128) {
    float4 v = *(const float4*)&tbuf[(((size_t)(b * 4 + m)) * 1024 + l0) * 16 + tid * 4];
    *(float4*)&ts[tid >> 2][(tid & 3) * 4] = v;
  }
  float w2c[3][16];
  #pragma unroll
  for (int dd = 0; dd < 3; dd++) {
    const int d = tid + 256 * dd;
    #pragma unroll
    for (int rq = 0; rq < 4; rq++)
      *(float4*)&w2c[dd][rq * 4] = *(const float4*)&w2g[((size_t)mi * 768 + d) * 16 + rq * 4];
  }
  __syncthreads();
  for (int p = 0; p < 32; p++) {
    float tv[16];
    #pragma unroll
    for (int rq = 0; rq < 4; rq++) *(float4*)&tv[rq * 4] = *(const float4*)&ts[p][rq * 4];
    const int t = (l0 + p) * 4 + m;
    const size_t o = ((size_t)b * LM + t) * D2;
    #pragma unroll
    for (int dd = 0; dd < 3; dd++) {
      float a = 0.f;
      #pragma unroll
      for (int r2 = 0; r2 < 16; r2++) a += tv[r2] * w2c[dd][r2];
      const int d = tid + 256 * dd;
      if (d < D2) xr[o + d] = a;
      else        zr[o + d - D2] = a;
    }
  }
}

// ---------------------------------------------------------------------------
// K2 (rebuilt): conv_x + SiLU then x_dbl = xc @ x_proj_w^T.
// Thread = (og 0..31, ksl 0..7): 2 outputs x 48 k (k-set ksl+8i interleaved
// -> wave's 8 distinct float4 reads span all 32 banks exactly once:
// conflict-free, 8-lane broadcast).  Weights in 96 VGPRs (global, L2-hot).
// Per-ksl partials in LDS (pad 65 -> ~2-way on writes = free), tiny reduce.
// LDS 58 KB -> 2 blocks/CU.  grid (LM/16, B) = (256,4), block 256.
// ---------------------------------------------------------------------------
__global__ __launch_bounds__(256) void k2_xdbl(
    const float* __restrict__ xr, const float* __restrict__ xw,
    const float* __restrict__ cwx, float* __restrict__ xdbl)
{
  __shared__ float xcl[16][388];
  __shared__ float part[16][8][65];
  const int tid = threadIdx.x;
  const int t0 = blockIdx.x * 16;
  const int b  = blockIdx.y;
  const int og  = tid >> 3;       // 0..31 -> outputs og*2, og*2+1
  const int ksl = tid & 7;        // k-slice

  // weights for 2 outputs over the interleaved k-set (ksl + 8*i)*4 .. +3
  float4 w0[12], w1[12];
  {
    const float* wp0 = xw + (size_t)(og * 2 + 0) * 384;
    const float* wp1 = xw + (size_t)(og * 2 + 1) * 384;
    #pragma unroll
    for (int i = 0; i < 12; i++) {
      w0[i] = *(const float4*)&wp0[(ksl + i * 8) * 4];
      w1[i] = *(const float4*)&wp1[(ksl + i * 8) * 4];
    }
  }
  // stage conv+silu (coalesced: consecutive threads -> consecutive d)
  for (int i = tid; i < 16 * 384; i += 256) {
    const int tt = i / 384, d = i % 384;
    const int t = t0 + tt;
    const size_t base = (size_t)b * LM * D2 + d;
    float xm = (t > 0)      ? xr[base + (size_t)(t - 1) * D2] : 0.f;
    float x0 =                xr[base + (size_t)t * D2];
    float xp = (t + 1 < LM) ? xr[base + (size_t)(t + 1) * D2] : 0.f;
    float v = cwx[d * 3] * xm + cwx[d * 3 + 1] * x0 + cwx[d * 3 + 2] * xp;
    xcl[tt][d] = siluf_(v);
  }
  __syncthreads();

  for (int tt = 0; tt < 16; tt++) {
    float acc0 = 0.f, acc1 = 0.f;
    #pragma unroll
    for (int i = 0; i < 12; i++) {
      const float4 x = *(const float4*)&xcl[tt][(ksl + i * 8) * 4];
      acc0 += x.x * w0[i].x + x.y * w0[i].y + x.z * w0[i].z + x.w * w0[i].w;
      acc1 += x.x * w1[i].x + x.y * w1[i].y + x.z * w1[i].z + x.w * w1[i].w;
    }
    part[tt][ksl][og * 2]     = acc0;
    part[tt][ksl][og * 2 + 1] = acc1;
  }
  __syncthreads();

  #pragma unroll
  for (int r = 0; r < 4; r++) {
    const int idx = tid + r * 256;      // 1024 (t,o) pairs
    const int tt = idx >> 6, o = idx & 63;
    float s = 0.f;
    #pragma unroll
    for (int k = 0; k < 8; k++) s += part[tt][k][o];
    xdbl[((size_t)b * LM + t0 + tt) * 64 + o] = s;
  }
}

// ---------------------------------------------------------------------------
// K3: delta = softplus(x_dbl[:, :48] @ dt_proj_w^T + 2*dt_proj_b)
//     (bias added twice, faithful to the reference).  Thread-per-d, weights
//     in registers, 6 KB LDS.
// grid (LM/32, B), block 384.
// ---------------------------------------------------------------------------
__global__ __launch_bounds__(384) void k3_delta(
    const float* __restrict__ xdbl, const float* __restrict__ dtw,
    const float* __restrict__ dtb, float* __restrict__ delta)
{
  __shared__ float xt[32][48];
  const int tid = threadIdx.x;     // = d
  const int t0 = blockIdx.x * 32;
  const int b  = blockIdx.y;
  for (int i = tid; i < 32 * 12; i += 384) {
    int tt = i / 12, c = (i % 12) * 4;
    *(float4*)&xt[tt][c] = *(const float4*)&xdbl[((size_t)b * LM + t0 + tt) * 64 + c];
  }
  float wc[48];
  #pragma unroll
  for (int rq = 0; rq < 12; rq++)
    *(float4*)&wc[rq * 4] = *(const float4*)&dtw[(size_t)tid * 48 + rq * 4];
  const float bias2 = 2.f * dtb[tid];
  __syncthreads();
  for (int p = 0; p < 32; p++) {
    float acc = 0.f;
    #pragma unroll
    for (int r2 = 0; r2 < 48; r2++) acc += xt[p][r2] * wc[r2];
    delta[((size_t)b * LM + t0 + p) * D2 + tid] = softplusf_(acc + bias2);
  }
}

// ---------------------------------------------------------------------------
// S1: per-chunk scan aggregates.  768 threads: (d, state-half).
// A_log = log(1..8) in practice -> dA[s] = q^(s+1), one exp (runtime-checked).
// grid (NCHK2, B) = (128,4) -> 2 blocks/CU, 24 waves/CU.
// ---------------------------------------------------------------------------
__global__ __launch_bounds__(768) void s1_scan(
    const float* __restrict__ xr, const float* __restrict__ delta,
    const float* __restrict__ xdbl, const float* __restrict__ alog,
    const float* __restrict__ cwx, float* __restrict__ aP, float* __restrict__ bAg)
{
  __shared__ float Bs[TC2][8];
  const int tid = threadIdx.x;
  const int half = tid >= 384 ? 1 : 0;   // wave-uniform (384 = 6 waves)
  const int d = tid - half * 384;
  const int c = blockIdx.x, b = blockIdx.y;
  const int t0 = c * TC2;
  if (tid < TC2 * 8) {
    const int tt = tid >> 3, s = tid & 7;
    Bs[tt][s] = xdbl[((size_t)b * LM + t0 + tt) * 64 + 48 + s];
  }
  const float a1 = -expf(alog[d * 8]);     // s=0 rate
  float a[4];
  bool geo = true;
  #pragma unroll
  for (int s = 0; s < 4; s++) {
    a[s] = -expf(alog[d * 8 + half * 4 + s]);
    const float ex = (float)(half * 4 + s + 1) * a1;
    geo = geo && (fabsf(a[s] - ex) <= 1e-4f * fabsf(a[s]));
  }
  const float w0 = cwx[d * 3], w1 = cwx[d * 3 + 1], w2 = cwx[d * 3 + 2];
  const float* xp = xr + (size_t)b * LM * D2 + d;
  const float* dp = delta + (size_t)b * LM * D2 + d;
  float xm = (t0 > 0) ? xp[(size_t)(t0 - 1) * D2] : 0.f;
  float x0 = xp[(size_t)t0 * D2];
  float h[4] = {};
  float ap[4] = {1.f, 1.f, 1.f, 1.f};
  __syncthreads();
  #pragma unroll 4
  for (int tt = 0; tt < TC2; tt++) {
    const int t = t0 + tt;
    const float xn = (t + 1 < LM) ? xp[(size_t)(t + 1) * D2] : 0.f;
    const float xc = siluf_(w0 * xm + w1 * x0 + w2 * xn);
    const float dv = dp[(size_t)t * D2];
    float dA[4];
    if (geo) {
      const float q = expf(dv * a1);
      const float q2 = q * q, q4 = q2 * q2;
      if (half == 0) { dA[0] = q;      dA[1] = q2;      dA[2] = q2 * q;      dA[3] = q4; }
      else           { dA[0] = q4 * q; dA[1] = q4 * q2; dA[2] = q4 * q2 * q; dA[3] = q4 * q4; }
    } else {
      #pragma unroll
      for (int s = 0; s < 4; s++) dA[s] = expf(dv * a[s]);
    }
    const float dx = dv * xc;
    #pragma unroll
    for (int s = 0; s < 4; s++) {
      ap[s] *= dA[s];
      h[s] = dA[s] * h[s] + dx * Bs[tt][half * 4 + s];
    }
    xm = x0; x0 = xn;
  }
  const size_t o = (((size_t)b * NCHK2 + c) * 8 + half * 4) * D2 + d;
  #pragma unroll
  for (int s = 0; s < 4; s++) { aP[o + (size_t)s * D2] = ap[s]; bAg[o + (size_t)s * D2] = h[s]; }
}

// ---------------------------------------------------------------------------
// S2: exclusive scan over chunk aggregates -> initial h per chunk, written
// IN PLACE over aP.  12288 threads.
// ---------------------------------------------------------------------------
__global__ __launch_bounds__(256) void s2_combine(
    float* __restrict__ aP, const float* __restrict__ bAg)
{
  const int idx = blockIdx.x * 256 + threadIdx.x;   // 0..12287
  const int d = idx % 384;
  const int s = (idx / 384) & 7;
  const int b = idx / 3072;
  float h = 0.f;
  #pragma unroll 4
  for (int c = 0; c < NCHK2; c++) {
    const size_t o = (((size_t)b * NCHK2 + c) * 8 + s) * D2 + d;
    const float av = aP[o], bv = bAg[o];
    aP[o] = h;                     // hI
    h = av * h + bv;
  }
}

// ---------------------------------------------------------------------------
// WCONV: out_w (4 x 768 x 384 fp32) -> bf16 (aliases dead tbuf region).
// ---------------------------------------------------------------------------
__global__ __launch_bounds__(256) void wconv(
    const float* __restrict__ w, short* __restrict__ w16)
{
  const int i = (blockIdx.x * 256 + threadIdx.x) * 4;   // < 1179648
  const float4 v = *(const float4*)&w[i];
  ushort4 o;
  o.x = (unsigned short)f2b_(v.x);
  o.y = (unsigned short)f2b_(v.y);
  o.z = (unsigned short)f2b_(v.z);
  o.w = (unsigned short)f2b_(v.w);
  *(ushort4*)&w16[i] = o;
}

// ---------------------------------------------------------------------------
// S3: rescan + y + RMSNorm + silu(silu(conv_z)) gate.  32-step chunks;
// LDS ~52 KB -> 2 blocks/CU.  Writes Yg (aliases delta; per-row reads of
// delta precede the row's write).
// grid (NCHK2, B), block 384.
// ---------------------------------------------------------------------------
__global__ __launch_bounds__(384) void s3_rescan(
    const float* __restrict__ xr, const float* __restrict__ zr,
    const float* delta_in, const float* __restrict__ xdbl,
    const float* __restrict__ hI, const float* __restrict__ alog,
    const float* __restrict__ cwx, const float* __restrict__ cwz,
    const float* __restrict__ Dv, const float* __restrict__ nw,
    float* Yg)
{
  __shared__ float Bs[TC2][8];
  __shared__ float Cs[TC2][8];
  __shared__ float yt[TC2][389];
  __shared__ float part[TC2][12];
  __shared__ float rinv[TC2];
  const int tid = threadIdx.x;
  const int d = tid;
  const int c = blockIdx.x, b = blockIdx.y;
  const int t0 = c * TC2;
  if (tid < TC2 * 8) {
    const int tt = tid >> 3, s = tid & 7;
    const size_t o = ((size_t)b * LM + t0 + tt) * 64;
    Bs[tt][s] = xdbl[o + 48 + s];
    Cs[tt][s] = xdbl[o + 56 + s];
  }
  const float a1 = -expf(alog[d * 8]);
  float a[8];
  bool geo = true;
  #pragma unroll
  for (int s = 0; s < 8; s++) {
    a[s] = -expf(alog[d * 8 + s]);
    const float ex = (float)(s + 1) * a1;
    geo = geo && (fabsf(a[s] - ex) <= 1e-4f * fabsf(a[s]));
  }
  float h[8];
  const size_t ho = (((size_t)b * NCHK2 + c) * 8) * D2 + d;
  #pragma unroll
  for (int s = 0; s < 8; s++) h[s] = hI[ho + (size_t)s * D2];
  const float wx0 = cwx[d * 3], wx1 = cwx[d * 3 + 1], wx2 = cwx[d * 3 + 2];
  const float wz0 = cwz[d * 3], wz1 = cwz[d * 3 + 1], wz2 = cwz[d * 3 + 2];
  const float Dd = Dv[d], nwd = nw[d];
  const float* xp = xr + (size_t)b * LM * D2 + d;
  const float* zp = zr + (size_t)b * LM * D2 + d;
  const float* dp = delta_in + (size_t)b * LM * D2 + d;
  float xm = (t0 > 0) ? xp[(size_t)(t0 - 1) * D2] : 0.f;
  float x0 = xp[(size_t)t0 * D2];
  __syncthreads();

  #pragma unroll 4
  for (int tt = 0; tt < TC2; tt++) {
    const int t = t0 + tt;
    const float xn = (t + 1 < LM) ? xp[(size_t)(t + 1) * D2] : 0.f;
    const float xc = siluf_(wx0 * xm + wx1 * x0 + wx2 * xn);
    const float dv = dp[(size_t)t * D2];
    float dA[8];
    if (geo) {
      const float q = expf(dv * a1);
      const float q2 = q * q, q4 = q2 * q2;
      dA[0] = q;      dA[1] = q2;      dA[2] = q2 * q;      dA[3] = q4;
      dA[4] = q4 * q; dA[5] = q4 * q2; dA[6] = q4 * q2 * q; dA[7] = q4 * q4;
    } else {
      #pragma unroll
      for (int s = 0; s < 8; s++) dA[s] = expf(dv * a[s]);
    }
    const float dx = dv * xc;
    float yv = 0.f;
    #pragma unroll
    for (int s = 0; s < 8; s++) {
      h[s] = dA[s] * h[s] + dx * Bs[tt][s];
      yv += h[s] * Cs[tt][s];
    }
    yv += Dd * xc;
    yt[tt][d] = yv;
    xm = x0; x0 = xn;
  }
  __syncthreads();
  {
    const int tr = tid & 31, j = tid >> 5;   // 12 k-groups of 32
    float sum = 0.f;
    #pragma unroll
    for (int k = 0; k < 32; k++) { const float v = yt[tr][j * 32 + k]; sum += v * v; }
    part[tr][j] = sum;
  }
  __syncthreads();
  if (tid < TC2) {
    float sm = 0.f;
    #pragma unroll
    for (int j = 0; j < 12; j++) sm += part[tid][j];
    rinv[tid] = rsqrtf(sm * (1.f / 384.f) + 1e-5f);
  }
  __syncthreads();
  float zm = (t0 > 0) ? zp[(size_t)(t0 - 1) * D2] : 0.f;
  float z0 = zp[(size_t)t0 * D2];
  #pragma unroll 4
  for (int tt = 0; tt < TC2; tt++) {
    const int t = t0 + tt;
    const float zn = (t + 1 < LM) ? zp[(size_t)(t + 1) * D2] : 0.f;
    // reference: zT = silu(conv_z(z)); gate = silu(zT) -> SiLU twice
    const float zc = siluf_(siluf_(wz0 * zm + wz1 * z0 + wz2 * zn));
    Yg[((size_t)b * LM + t) * D2 + d] = yt[tt][d] * rinv[tt] * nwd * zc;
    zm = z0; z0 = zn;
  }
}

// ---------------------------------------------------------------------------
// K4 (MFMA): out = scale * Yg @ out_w[m]^T via mfma_f32_16x16x32_bf16.
// grid (8, 6, 16), block 256.
// ---------------------------------------------------------------------------
__global__ __launch_bounds__(256) void k4_mfma(
    const float* __restrict__ Yg, const short* __restrict__ W16,
    const int* __restrict__ midx, const float* __restrict__ scalep,
    float* __restrict__ out)
{
  const int tid = threadIdx.x;
  const int wid = tid >> 6, lane = tid & 63;
  const int lt = blockIdx.x, ot = blockIdx.y, bm = blockIdx.z;
  const int b = bm >> 2, m = bm & 3;
  const int mi = midx[m];
  const int l0 = lt * 128, o0 = ot * 128;
  const int wr = wid >> 1, wc = wid & 1;        // 64x64 quadrant per wave
  const int lr = lane & 15, lg = lane >> 4;     // frag row / k-group
  const float scale = scalep[0];

  const float* Ab = Yg + (size_t)b * LM * D2;             // row l at t=l*4+m
  const short* Bb = W16 + (size_t)mi * 768 * D2;

  f32x4 acc[4][4];
  #pragma unroll
  for (int i = 0; i < 4; i++)
    #pragma unroll
    for (int j = 0; j < 4; j++) acc[i][j] = (f32x4){0.f, 0.f, 0.f, 0.f};

  for (int k0 = 0; k0 < D2; k0 += 32) {
    const int kk = k0 + lg * 8;
    short8b afr[4], bfr[4];
    #pragma unroll
    for (int mr = 0; mr < 4; mr++) {
      const int row = l0 + wr * 64 + mr * 16 + lr;
      const float* ap = Ab + (size_t)(row * 4 + m) * D2 + kk;
      const f32x4 a0 = *(const f32x4*)ap;
      const f32x4 a1 = *(const f32x4*)(ap + 4);
      short8b af;
      af[0] = f2b_(a0.x); af[1] = f2b_(a0.y); af[2] = f2b_(a0.z); af[3] = f2b_(a0.w);
      af[4] = f2b_(a1.x); af[5] = f2b_(a1.y); af[6] = f2b_(a1.z); af[7] = f2b_(a1.w);
      afr[mr] = af;
    }
    #pragma unroll
    for (int nr = 0; nr < 4; nr++) {
      const int col = o0 + wc * 64 + nr * 16 + lr;
      bfr[nr] = *(const short8b*)(Bb + (size_t)col * D2 + kk);
    }
    #pragma unroll
    for (int mr = 0; mr < 4; mr++)
      #pragma unroll
      for (int nr = 0; nr < 4; nr++)
        acc[mr][nr] = __builtin_amdgcn_mfma_f32_16x16x32_bf16(
            afr[mr], bfr[nr], acc[mr][nr], 0, 0, 0);
  }

  #pragma unroll
  for (int mr = 0; mr < 4; mr++) {
    #pragma unroll
    for (int r = 0; r < 4; r++) {
      const int row = l0 + wr * 64 + mr * 16 + lg * 4 + r;
      const size_t ob = (((size_t)(b * 4 + m)) * 1024 + row) * 768;
      #pragma unroll
      for (int nr = 0; nr < 4; nr++) {
        const int col = o0 + wc * 64 + nr * 16 + lr;
        out[ob + col] = acc[mr][nr][r] * scale;
      }
    }
  }
}

// ---------------------------------------------------------------------------
extern "C" void kernel_launch(void* const* d_in, const int* in_sizes, int n_in,
                              void* d_out, int out_size, void* d_ws, size_t ws_size,
                              hipStream_t stream)
{
  const float* hs   = (const float*)d_in[0];
  const float* w1   = (const float*)d_in[1];
  const float* lng  = (const float*)d_in[2];
  const float* lnb  = (const float*)d_in[3];
  const float* w2   = (const float*)d_in[4];
  const float* xw   = (const float*)d_in[5];
  const float* dtw  = (const float*)d_in[6];
  const float* dtb  = (const float*)d_in[7];
  const float* alog = (const float*)d_in[8];
  const float* Dv   = (const float*)d_in[9];
  const float* cwx  = (const float*)d_in[10];
  const float* cwz  = (const float*)d_in[11];
  const float* nw   = (const float*)d_in[12];
  const float* ow   = (const float*)d_in[13];
  const float* sc   = (const float*)d_in[14];
  const int*   midx = (const int*)d_in[15];
  float* out = (float*)d_out;

  float* ws = (float*)d_ws;
  const size_t NE = (size_t)4 * LM * D2;          // 6.29M floats
  float* xr    = ws;
  float* zr    = xr + NE;
  float* delta = zr + NE;                          // later reused as Yg (safe)
  float* xdbl  = delta + NE;                       // 4*4096*64 = 1.05M floats
  float* tbuf  = xdbl + (size_t)4 * LM * 64;       // k1 intermediate, 1.05M floats
  short* owb16 = (short*)tbuf;                     // tbuf dead after k1b

  // chunk aggregates live in d_out (50 MB; fully rewritten by k4 at the end):
  float* aP  = out;                                // 4*128*8*384 = 1.57M floats
  float* bAg = aP + (size_t)4 * NCHK2 * 8 * D2;    // another 1.57M floats
  float* hI  = aP;                                 // s2 writes hI in place

  k1a_proj<<<dim3(64, 4, 4), 256, 0, stream>>>(hs, w1, lng, lnb, midx, tbuf);
  k1b_xz<<<dim3(32, 4, 4), 256, 0, stream>>>(tbuf, w2, midx, xr, zr);
  k2_xdbl<<<dim3(256, 4), 256, 0, stream>>>(xr, xw, cwx, xdbl);
  k3_delta<<<dim3(128, 4), 384, 0, stream>>>(xdbl, dtw, dtb, delta);
  s1_scan<<<dim3(NCHK2, 4), 768, 0, stream>>>(xr, delta, xdbl, alog, cwx, aP, bAg);
  s2_combine<<<48, 256, 0, stream>>>(aP, bAg);
  wconv<<<1152, 256, 0, stream>>>(ow, owb16);      // after k1b (tbuf dead)
  s3_rescan<<<dim3(NCHK2, 4), 384, 0, stream>>>(xr, zr, delta, xdbl, hI, alog, cwx, cwz, Dv, nw, delta);
  k4_mfma<<<dim3(8, 6, 16), 256, 0, stream>>>(delta, owb16, midx, sc, out);
}